// Round 1
// baseline (3743.191 us; speedup 1.0000x reference)
//
#include <hip/hip_runtime.h>

#define CIN_  128
#define C_    256
#define HW_   1024      /* 32*32 */
#define NPC_  65536.0f  /* 64*1024 elements per channel for BN stats */
#define NB_   16384     /* 64 batches * 256 channels */

constexpr size_t NELEM = 16777216ull;   // 64*256*32*32

// ---- module-scope device scratch ------------------------------------------
__device__ float g_sel[8];
__device__ float g_stats[8 * 512];      // per-slot: [0..255]=sum, [256..511]=sumsq
__device__ int   g_isf32;
__device__ float g_h[NELEM];            // 67 MB
__device__ float g_acc[NELEM];          // 67 MB
__device__ float g_tmp[NELEM];          // 67 MB  (conv3x3 out / trans out / pools-max / pw out)
__device__ float g_tmp2[NELEM];         // 67 MB  (conv5x5 out / pools-avg)
__device__ float g_tmp3[NELEM];         // 67 MB  (dil conv out)

__device__ __forceinline__ float u2f(unsigned short u) {
    union { unsigned int i; float f; } x; x.i = ((unsigned int)u) << 16; return x.f;
}
__device__ __forceinline__ unsigned short f2u(float f) {
    union { float f; unsigned int i; } x; x.f = f;
    unsigned int r = x.i + 0x7fffu + ((x.i >> 16) & 1u);  // RNE
    return (unsigned short)(r >> 16);
}
__device__ __forceinline__ float ldq(const void* p, long i, int isf32) {
    return isf32 ? ((const float*)p)[i] : u2f(((const unsigned short*)p)[i]);
}

// ---------------------------------------------------------------------------
// prep: zero stats, detect input dtype, compute sel
// ---------------------------------------------------------------------------
__global__ void k_prep(const void* __restrict__ x, const void* __restrict__ aw) {
    __shared__ int flag_s;
    __shared__ float red[256];
    const int t = threadIdx.x;
    for (int i = t; i < 8 * 512; i += 256) g_stats[i] = 0.f;
    const unsigned short* xu = (const unsigned short*)x;
    int bad = 0;
    for (int i = t; i < 8192; i += 256) {
        unsigned int e = (xu[i] >> 7) & 0xFFu;
        if (e >= 0xC6u) ++bad;
    }
    red[t] = (float)bad;
    __syncthreads();
    for (int off = 128; off > 0; off >>= 1) {
        if (t < off) red[t] += red[t + off];
        __syncthreads();
    }
    if (t == 0) { flag_s = (red[0] > 4.0f) ? 1 : 0; g_isf32 = flag_s; }
    __syncthreads();
    const int isf32 = flag_s;
    if (t == 0) {
        float w[8];
        float mx = -1e30f;
        for (int i = 0; i < 8; ++i) { w[i] = ldq(aw, i, isf32); mx = fmaxf(mx, w[i]); }
        float s = 0.f;
        for (int i = 0; i < 8; ++i) { w[i] = expf(w[i] - mx); s += w[i]; }
        for (int i = 0; i < 8; ++i) w[i] /= s;
        float sv[8] = {0,0,0,0,0,0,0,0};
        bool used[8] = {false,false,false,false,false,false,false,false};
        for (int k = 0; k < 3; ++k) {          // top-3, first-index tie-break
            int bi = -1; float bv = -1.f;
            for (int i = 0; i < 8; ++i) if (!used[i] && w[i] > bv) { bv = w[i]; bi = i; }
            used[bi] = true; sv[bi] = bv;
        }
        float tot = 0.f;
        for (int i = 0; i < 8; ++i) { if (sv[i] < 0.01f) sv[i] = 0.f; tot += sv[i]; }
        tot = fmaxf(tot, 1e-12f);
        for (int i = 0; i < 8; ++i) g_sel[i] = sv[i] / tot;
    }
}

// ---------------------------------------------------------------------------
// stats epilogues: single-channel (red[512]) and channel-pair (red[1024])
// ---------------------------------------------------------------------------
__device__ __forceinline__ void stats_epilogue(float* red, float s, float s2,
                                               int t, int c, int slot) {
    __syncthreads();
    red[t] = s; red[t + 256] = s2;
    __syncthreads();
    for (int off = 128; off > 0; off >>= 1) {
        if (t < off) { red[t] += red[t + off]; red[t + 256] += red[t + 256 + off]; }
        __syncthreads();
    }
    if (t == 0) {
        atomicAdd(&g_stats[slot * 512 + c], red[0]);
        atomicAdd(&g_stats[slot * 512 + 256 + c], red[256]);
    }
}

__device__ __forceinline__ void stats_ep2(float* red, int t,
                                          float sA, float s2A, float sB, float s2B,
                                          int cA, int cB, int slot) {
    __syncthreads();
    red[t] = sA; red[t + 256] = s2A; red[t + 512] = sB; red[t + 768] = s2B;
    __syncthreads();
    for (int off = 128; off > 0; off >>= 1) {
        if (t < off) {
            red[t]       += red[t + off];
            red[t + 256] += red[t + 256 + off];
            red[t + 512] += red[t + 512 + off];
            red[t + 768] += red[t + 768 + off];
        }
        __syncthreads();
    }
    if (t == 0) {
        atomicAdd(&g_stats[slot * 512 + cA],       red[0]);
        atomicAdd(&g_stats[slot * 512 + 256 + cA], red[256]);
        atomicAdd(&g_stats[slot * 512 + cB],       red[512]);
        atomicAdd(&g_stats[slot * 512 + 256 + cB], red[768]);
    }
}

// ---------------------------------------------------------------------------
// transition 1x1 conv, COUT=8 per block (staging amortized 8x) -> g_tmp, slot 0
// grid = 64 b * 32 cgroups = 2048
// ---------------------------------------------------------------------------
__global__ __launch_bounds__(256)
void k_trans(const void* __restrict__ xin, const void* __restrict__ wt) {
    __shared__ float xs[HW_];
    __shared__ float red[1024];
    const int t = threadIdx.x;
    const int c0 = (blockIdx.x & 31) * 8;
    const int b  = blockIdx.x >> 5;
    const int isf32 = g_isf32;
    float acc[8][4];
    #pragma unroll
    for (int k = 0; k < 8; ++k)
        #pragma unroll
        for (int j = 0; j < 4; ++j) acc[k][j] = 0.f;
    for (int ci = 0; ci < CIN_; ++ci) {
        __syncthreads();
        size_t vi = (size_t)(b * CIN_ + ci) * 256 + t;
        if (isf32) {
            float4 r = ((const float4*)xin)[vi];
            xs[t*4+0] = r.x; xs[t*4+1] = r.y; xs[t*4+2] = r.z; xs[t*4+3] = r.w;
        } else {
            ushort4 r = ((const ushort4*)xin)[vi];
            xs[t*4+0] = u2f(r.x); xs[t*4+1] = u2f(r.y);
            xs[t*4+2] = u2f(r.z); xs[t*4+3] = u2f(r.w);
        }
        __syncthreads();
        const float x0v = xs[t], x1v = xs[t + 256], x2v = xs[t + 512], x3v = xs[t + 768];
        #pragma unroll
        for (int k = 0; k < 8; ++k) {
            float wv = ldq(wt, (long)(c0 + k) * CIN_ + ci, isf32);
            acc[k][0] += x0v * wv; acc[k][1] += x1v * wv;
            acc[k][2] += x2v * wv; acc[k][3] += x3v * wv;
        }
    }
    #pragma unroll
    for (int k = 0; k < 8; ++k) {
        float* o = g_tmp + (size_t)(b * C_ + c0 + k) * HW_;
        o[t] = acc[k][0]; o[t + 256] = acc[k][1];
        o[t + 512] = acc[k][2]; o[t + 768] = acc[k][3];
    }
    #pragma unroll
    for (int k = 0; k < 8; k += 2) {
        float sA  = acc[k][0] + acc[k][1] + acc[k][2] + acc[k][3];
        float s2A = acc[k][0]*acc[k][0] + acc[k][1]*acc[k][1]
                  + acc[k][2]*acc[k][2] + acc[k][3]*acc[k][3];
        float sB  = acc[k+1][0] + acc[k+1][1] + acc[k+1][2] + acc[k+1][3];
        float s2B = acc[k+1][0]*acc[k+1][0] + acc[k+1][1]*acc[k+1][1]
                  + acc[k+1][2]*acc[k+1][2] + acc[k+1][3]*acc[k+1][3];
        stats_ep2(red, t, sA, s2A, sB, s2B, c0 + k, c0 + k + 1, 0);
    }
}

// ---------------------------------------------------------------------------
// h = relu(BN0(g_tmp)) -> g_h ; fused: g_acc = sel[3] * h (skip-branch init)
// ---------------------------------------------------------------------------
__global__ __launch_bounds__(256)
void k_bnrelu_init(const void* __restrict__ g, const void* __restrict__ bb) {
    size_t idx = ((size_t)blockIdx.x * 256 + threadIdx.x) * 4;
    int c = (int)((idx >> 10) & (C_ - 1));
    int isf32 = g_isf32;
    float s3 = g_sel[3];
    float mean = g_stats[c] * (1.0f / NPC_);
    float var  = g_stats[256 + c] * (1.0f / NPC_) - mean * mean;
    float rstd = rsqrtf(fmaxf(var, 0.f) + 1e-5f);
    float gv = ldq(g, c, isf32), bv = ldq(bb, c, isf32);
    float4 r = *(const float4*)(g_tmp + idx);
    float4 h;
    h.x = fmaxf(0.f, (r.x - mean) * rstd * gv + bv);
    h.y = fmaxf(0.f, (r.y - mean) * rstd * gv + bv);
    h.z = fmaxf(0.f, (r.z - mean) * rstd * gv + bv);
    h.w = fmaxf(0.f, (r.w - mean) * rstd * gv + bv);
    *(float4*)(g_h + idx) = h;
    float4 a; a.x = s3 * h.x; a.y = s3 * h.y; a.z = s3 * h.z; a.w = s3 * h.w;
    *(float4*)(g_acc + idx) = a;
}

// ---------------------------------------------------------------------------
// fused max+avg 3x3 pooling on g_h (one staging pass, two outputs)
// max -> g_tmp (slot 1), avg -> g_tmp2 (slot 2). stride-33 LDS (2-way, free)
// ---------------------------------------------------------------------------
__global__ __launch_bounds__(256)
void k_pool_fused() {
    const float s1 = g_sel[1], s2 = g_sel[2];
    if (s1 == 0.f && s2 == 0.f) return;
    __shared__ float xs[34 * 33];
    __shared__ float red[512];
    const int t = threadIdx.x;
    const int c = blockIdx.x & (C_ - 1);
    const int y  = t >> 3;
    const int x0 = (t & 7) * 4;
    const float* hp = g_h + (size_t)blockIdx.x * HW_;
    float4 r = *(const float4*)(hp + t * 4);
    float* xw = xs + y * 33 + x0;
    xw[0] = r.x; xw[1] = r.y; xw[2] = r.z; xw[3] = r.w;
    __syncthreads();
    float mx[4] = {0.f, 0.f, 0.f, 0.f};       // h >= 0 post-ReLU; matches padded max
    float sm[4] = {0.f, 0.f, 0.f, 0.f};
    #pragma unroll
    for (int ky = 0; ky < 3; ++ky) {
        int iy = y + ky - 1;
        if (iy < 0 || iy >= 32) continue;
        float row[6];
        #pragma unroll
        for (int i = 0; i < 6; ++i) {
            int ix = x0 + i - 1;
            row[i] = (ix >= 0 && ix < 32) ? xs[iy * 33 + ix] : 0.0f;
        }
        #pragma unroll
        for (int kx = 0; kx < 3; ++kx)
            #pragma unroll
            for (int j = 0; j < 4; ++j) {
                mx[j] = fmaxf(mx[j], row[j + kx]);
                sm[j] += row[j + kx];
            }
    }
    #pragma unroll
    for (int j = 0; j < 4; ++j) sm[j] *= (1.0f / 9.0f);
    const size_t ob = (size_t)blockIdx.x * HW_ + y * 32 + x0;
    if (s1 != 0.f) {
        float* o = g_tmp + ob;
        o[0] = mx[0]; o[1] = mx[1]; o[2] = mx[2]; o[3] = mx[3];
        stats_epilogue(red, mx[0]+mx[1]+mx[2]+mx[3],
                       mx[0]*mx[0]+mx[1]*mx[1]+mx[2]*mx[2]+mx[3]*mx[3], t, c, 1);
    }
    if (s2 != 0.f) {
        float* o = g_tmp2 + ob;
        o[0] = sm[0]; o[1] = sm[1]; o[2] = sm[2]; o[3] = sm[3];
        stats_epilogue(red, sm[0]+sm[1]+sm[2]+sm[3],
                       sm[0]*sm[0]+sm[1]*sm[1]+sm[2]*sm[2]+sm[3]*sm[3], t, c, 2);
    }
}

// ---------------------------------------------------------------------------
// g_acc += sel1*BN1(g_tmp) + sel2*BN2(g_tmp2)   (fused pool BN-accumulate)
// ---------------------------------------------------------------------------
__global__ __launch_bounds__(256)
void k_bnacc2(const void* __restrict__ g1, const void* __restrict__ b1,
              const void* __restrict__ g2, const void* __restrict__ b2) {
    const float s1 = g_sel[1], s2 = g_sel[2];
    if (s1 == 0.f && s2 == 0.f) return;
    size_t idx = ((size_t)blockIdx.x * 256 + threadIdx.x) * 4;
    int c = (int)((idx >> 10) & (C_ - 1));
    int isf32 = g_isf32;
    float4 a = *(const float4*)(g_acc + idx);
    if (s1 != 0.f) {
        float mean = g_stats[512 + c] * (1.0f / NPC_);
        float var  = g_stats[512 + 256 + c] * (1.0f / NPC_) - mean * mean;
        float rstd = rsqrtf(fmaxf(var, 0.f) + 1e-5f);
        float gv = ldq(g1, c, isf32), bv = ldq(b1, c, isf32);
        float4 r = *(const float4*)(g_tmp + idx);
        a.x += s1 * ((r.x - mean) * rstd * gv + bv);
        a.y += s1 * ((r.y - mean) * rstd * gv + bv);
        a.z += s1 * ((r.z - mean) * rstd * gv + bv);
        a.w += s1 * ((r.w - mean) * rstd * gv + bv);
    }
    if (s2 != 0.f) {
        float mean = g_stats[2 * 512 + c] * (1.0f / NPC_);
        float var  = g_stats[2 * 512 + 256 + c] * (1.0f / NPC_) - mean * mean;
        float rstd = rsqrtf(fmaxf(var, 0.f) + 1e-5f);
        float gv = ldq(g2, c, isf32), bv = ldq(b2, c, isf32);
        float4 r = *(const float4*)(g_tmp2 + idx);
        a.x += s2 * ((r.x - mean) * rstd * gv + bv);
        a.y += s2 * ((r.y - mean) * rstd * gv + bv);
        a.z += s2 * ((r.z - mean) * rstd * gv + bv);
        a.w += s2 * ((r.w - mean) * rstd * gv + bv);
    }
    *(float4*)(g_acc + idx) = a;
}

// ---------------------------------------------------------------------------
// FUSED dense convs: conv3x3 (slot 4 -> g_tmp), conv5x5 (slot 5 -> g_tmp2),
// dil_conv3x3 (slot 7 -> g_tmp3). One staging + one 8-wide row gather feeds
// all three; COUT=2 output channels per block. grid = 64 b * 128 cg = 8192.
// Receptive-field nesting (row ix = x0+i-2, iy = y+io-2):
//   5x5: all io,  row[j+kx]        3x3: io 1..3, row[j+kx+1]
//   dil: io 0,2,4, row[j+2kx]
// ---------------------------------------------------------------------------
__global__ __launch_bounds__(256)
void k_conv_fused(const void* __restrict__ w3p, const void* __restrict__ w5p,
                  const void* __restrict__ wdp) {
    const bool h3 = (g_sel[4] != 0.f), h5 = (g_sel[5] != 0.f), hd = (g_sel[7] != 0.f);
    if (!h3 && !h5 && !hd) return;
    __shared__ float xs[34 * 33];
    __shared__ float red[1024];
    const int t  = threadIdx.x;
    const int c0 = (blockIdx.x & 127) * 2;
    const int b  = blockIdx.x >> 7;
    const int y  = t >> 3;
    const int x0 = (t & 7) * 4;
    const int isf32 = g_isf32;
    const float* hb = g_h + (size_t)b * C_ * HW_;
    // per-thread column offsets/masks, hoisted out of the ci loop
    int xoff[8]; int xok[8];
    #pragma unroll
    for (int i = 0; i < 8; ++i) {
        int ix = x0 + i - 2;
        xok[i]  = (ix >= 0 && ix < 32) ? 1 : 0;
        xoff[i] = ix < 0 ? 0 : (ix > 31 ? 31 : ix);
    }
    const long wb3_0 = (long)(c0 + 0) * C_ * 9,  wb3_1 = (long)(c0 + 1) * C_ * 9;
    const long wb5_0 = (long)(c0 + 0) * C_ * 25, wb5_1 = (long)(c0 + 1) * C_ * 25;
    float a3[2][4], a5[2][4], ad[2][4];
    #pragma unroll
    for (int u = 0; u < 2; ++u)
        #pragma unroll
        for (int j = 0; j < 4; ++j) { a3[u][j] = 0.f; a5[u][j] = 0.f; ad[u][j] = 0.f; }

    for (int ci = 0; ci < C_; ++ci) {
        __syncthreads();
        float4 r = *(const float4*)(hb + (size_t)ci * HW_ + t * 4);
        float* xw = xs + y * 33 + x0;
        xw[0] = r.x; xw[1] = r.y; xw[2] = r.z; xw[3] = r.w;
        __syncthreads();
        #pragma unroll
        for (int io = 0; io < 5; ++io) {
            const int iy  = y + io - 2;
            const int yok = (iy >= 0 && iy < 32) ? 1 : 0;
            const int yb  = (iy < 0 ? 0 : (iy > 31 ? 31 : iy)) * 33;
            float row[8];
            #pragma unroll
            for (int i = 0; i < 8; ++i) {
                float v = xs[yb + xoff[i]];          // clamped addr: always in-bounds
                row[i] = (yok & xok[i]) ? v : 0.f;   // zero-pad semantics
            }
            if (h5) {
                #pragma unroll
                for (int kx = 0; kx < 5; ++kx) {
                    float w0 = ldq(w5p, wb5_0 + (long)ci * 25 + io * 5 + kx, isf32);
                    float w1 = ldq(w5p, wb5_1 + (long)ci * 25 + io * 5 + kx, isf32);
                    #pragma unroll
                    for (int j = 0; j < 4; ++j) {
                        a5[0][j] += row[j + kx] * w0;
                        a5[1][j] += row[j + kx] * w1;
                    }
                }
            }
            if (h3 && io >= 1 && io <= 3) {
                const int ky = io - 1;
                #pragma unroll
                for (int kx = 0; kx < 3; ++kx) {
                    float w0 = ldq(w3p, wb3_0 + (long)ci * 9 + ky * 3 + kx, isf32);
                    float w1 = ldq(w3p, wb3_1 + (long)ci * 9 + ky * 3 + kx, isf32);
                    #pragma unroll
                    for (int j = 0; j < 4; ++j) {
                        a3[0][j] += row[j + kx + 1] * w0;
                        a3[1][j] += row[j + kx + 1] * w1;
                    }
                }
            }
            if (hd && (io & 1) == 0) {
                const int ky = io >> 1;
                #pragma unroll
                for (int kx = 0; kx < 3; ++kx) {
                    float w0 = ldq(wdp, wb3_0 + (long)ci * 9 + ky * 3 + kx, isf32);
                    float w1 = ldq(wdp, wb3_1 + (long)ci * 9 + ky * 3 + kx, isf32);
                    #pragma unroll
                    for (int j = 0; j < 4; ++j) {
                        ad[0][j] += row[j + 2 * kx] * w0;
                        ad[1][j] += row[j + 2 * kx] * w1;
                    }
                }
            }
        }
    }
    const size_t ob0 = (size_t)(b * C_ + c0 + 0) * HW_ + y * 32 + x0;
    const size_t ob1 = (size_t)(b * C_ + c0 + 1) * HW_ + y * 32 + x0;
    if (h3) {
        float4 o0; o0.x = a3[0][0]; o0.y = a3[0][1]; o0.z = a3[0][2]; o0.w = a3[0][3];
        float4 o1; o1.x = a3[1][0]; o1.y = a3[1][1]; o1.z = a3[1][2]; o1.w = a3[1][3];
        *(float4*)(g_tmp + ob0) = o0; *(float4*)(g_tmp + ob1) = o1;
        stats_ep2(red, t,
                  a3[0][0]+a3[0][1]+a3[0][2]+a3[0][3],
                  a3[0][0]*a3[0][0]+a3[0][1]*a3[0][1]+a3[0][2]*a3[0][2]+a3[0][3]*a3[0][3],
                  a3[1][0]+a3[1][1]+a3[1][2]+a3[1][3],
                  a3[1][0]*a3[1][0]+a3[1][1]*a3[1][1]+a3[1][2]*a3[1][2]+a3[1][3]*a3[1][3],
                  c0, c0 + 1, 4);
    }
    if (h5) {
        float4 o0; o0.x = a5[0][0]; o0.y = a5[0][1]; o0.z = a5[0][2]; o0.w = a5[0][3];
        float4 o1; o1.x = a5[1][0]; o1.y = a5[1][1]; o1.z = a5[1][2]; o1.w = a5[1][3];
        *(float4*)(g_tmp2 + ob0) = o0; *(float4*)(g_tmp2 + ob1) = o1;
        stats_ep2(red, t,
                  a5[0][0]+a5[0][1]+a5[0][2]+a5[0][3],
                  a5[0][0]*a5[0][0]+a5[0][1]*a5[0][1]+a5[0][2]*a5[0][2]+a5[0][3]*a5[0][3],
                  a5[1][0]+a5[1][1]+a5[1][2]+a5[1][3],
                  a5[1][0]*a5[1][0]+a5[1][1]*a5[1][1]+a5[1][2]*a5[1][2]+a5[1][3]*a5[1][3],
                  c0, c0 + 1, 5);
    }
    if (hd) {
        float4 o0; o0.x = ad[0][0]; o0.y = ad[0][1]; o0.z = ad[0][2]; o0.w = ad[0][3];
        float4 o1; o1.x = ad[1][0]; o1.y = ad[1][1]; o1.z = ad[1][2]; o1.w = ad[1][3];
        *(float4*)(g_tmp3 + ob0) = o0; *(float4*)(g_tmp3 + ob1) = o1;
        stats_ep2(red, t,
                  ad[0][0]+ad[0][1]+ad[0][2]+ad[0][3],
                  ad[0][0]*ad[0][0]+ad[0][1]*ad[0][1]+ad[0][2]*ad[0][2]+ad[0][3]*ad[0][3],
                  ad[1][0]+ad[1][1]+ad[1][2]+ad[1][3],
                  ad[1][0]*ad[1][0]+ad[1][1]*ad[1][1]+ad[1][2]*ad[1][2]+ad[1][3]*ad[1][3],
                  c0, c0 + 1, 7);
    }
}

// ---------------------------------------------------------------------------
// g_acc += s4*BN4(g_tmp) + s5*BN5(g_tmp2) + s7*BN7(g_tmp3)  (fused conv BN-acc)
// ---------------------------------------------------------------------------
__global__ __launch_bounds__(256)
void k_bnacc3(const void* __restrict__ g3, const void* __restrict__ b3,
              const void* __restrict__ g5, const void* __restrict__ b5,
              const void* __restrict__ gd, const void* __restrict__ bd) {
    const float s4 = g_sel[4], s5 = g_sel[5], s7 = g_sel[7];
    if (s4 == 0.f && s5 == 0.f && s7 == 0.f) return;
    size_t idx = ((size_t)blockIdx.x * 256 + threadIdx.x) * 4;
    int c = (int)((idx >> 10) & (C_ - 1));
    int isf32 = g_isf32;
    float4 a = *(const float4*)(g_acc + idx);
    if (s4 != 0.f) {
        float mean = g_stats[4 * 512 + c] * (1.0f / NPC_);
        float var  = g_stats[4 * 512 + 256 + c] * (1.0f / NPC_) - mean * mean;
        float rstd = rsqrtf(fmaxf(var, 0.f) + 1e-5f);
        float gv = ldq(g3, c, isf32), bv = ldq(b3, c, isf32);
        float4 r = *(const float4*)(g_tmp + idx);
        a.x += s4 * ((r.x - mean) * rstd * gv + bv);
        a.y += s4 * ((r.y - mean) * rstd * gv + bv);
        a.z += s4 * ((r.z - mean) * rstd * gv + bv);
        a.w += s4 * ((r.w - mean) * rstd * gv + bv);
    }
    if (s5 != 0.f) {
        float mean = g_stats[5 * 512 + c] * (1.0f / NPC_);
        float var  = g_stats[5 * 512 + 256 + c] * (1.0f / NPC_) - mean * mean;
        float rstd = rsqrtf(fmaxf(var, 0.f) + 1e-5f);
        float gv = ldq(g5, c, isf32), bv = ldq(b5, c, isf32);
        float4 r = *(const float4*)(g_tmp2 + idx);
        a.x += s5 * ((r.x - mean) * rstd * gv + bv);
        a.y += s5 * ((r.y - mean) * rstd * gv + bv);
        a.z += s5 * ((r.z - mean) * rstd * gv + bv);
        a.w += s5 * ((r.w - mean) * rstd * gv + bv);
    }
    if (s7 != 0.f) {
        float mean = g_stats[7 * 512 + c] * (1.0f / NPC_);
        float var  = g_stats[7 * 512 + 256 + c] * (1.0f / NPC_) - mean * mean;
        float rstd = rsqrtf(fmaxf(var, 0.f) + 1e-5f);
        float gv = ldq(gd, c, isf32), bv = ldq(bd, c, isf32);
        float4 r = *(const float4*)(g_tmp3 + idx);
        a.x += s7 * ((r.x - mean) * rstd * gv + bv);
        a.y += s7 * ((r.y - mean) * rstd * gv + bv);
        a.z += s7 * ((r.z - mean) * rstd * gv + bv);
        a.w += s7 * ((r.w - mean) * rstd * gv + bv);
    }
    *(float4*)(g_acc + idx) = a;
}

// ---------------------------------------------------------------------------
// depthwise 3x3 IN PLACE on g_h (runs LAST among h users) — stride-33 LDS
// ---------------------------------------------------------------------------
__global__ __launch_bounds__(256)
void k_dw_inplace(const void* __restrict__ wt) {
    if (g_sel[6] == 0.0f) return;
    __shared__ float xs[34 * 33];
    const int t = threadIdx.x;
    const int c = blockIdx.x & (C_ - 1);
    const int y  = t >> 3;
    const int x0 = (t & 7) * 4;
    const int isf32 = g_isf32;
    float* hp = g_h + (size_t)blockIdx.x * HW_;
    float4 r = *(const float4*)(hp + t * 4);
    float* xw = xs + y * 33 + x0;
    xw[0] = r.x; xw[1] = r.y; xw[2] = r.z; xw[3] = r.w;
    __syncthreads();
    float wv[9];
    #pragma unroll
    for (int k = 0; k < 9; ++k) wv[k] = ldq(wt, (long)c * 9 + k, isf32);
    float acc[4] = {0.f, 0.f, 0.f, 0.f};
    #pragma unroll
    for (int ky = 0; ky < 3; ++ky) {
        int iy = y + ky - 1;
        if (iy < 0 || iy >= 32) continue;
        float row[6];
        #pragma unroll
        for (int i = 0; i < 6; ++i) {
            int ix = x0 + i - 1;
            row[i] = (ix >= 0 && ix < 32) ? xs[iy * 33 + ix] : 0.0f;
        }
        #pragma unroll
        for (int kx = 0; kx < 3; ++kx)
            #pragma unroll
            for (int j = 0; j < 4; ++j)
                acc[j] += row[j + kx] * wv[ky * 3 + kx];
    }
    float* o = hp + y * 32 + x0;
    o[0] = acc[0]; o[1] = acc[1]; o[2] = acc[2]; o[3] = acc[3];
}

// ---------------------------------------------------------------------------
// pointwise 1x1 conv on g_h, COUT=8 per block -> g_tmp + fused stats slot 6
// grid = 64 b * 32 cgroups = 2048
// ---------------------------------------------------------------------------
__global__ __launch_bounds__(256)
void k_pw(const void* __restrict__ wt) {
    if (g_sel[6] == 0.0f) return;
    __shared__ float xs[HW_];
    __shared__ float red[1024];
    const int t = threadIdx.x;
    const int c0 = (blockIdx.x & 31) * 8;
    const int b  = blockIdx.x >> 5;
    const int isf32 = g_isf32;
    const float* hb = g_h + (size_t)b * C_ * HW_;
    float acc[8][4];
    #pragma unroll
    for (int k = 0; k < 8; ++k)
        #pragma unroll
        for (int j = 0; j < 4; ++j) acc[k][j] = 0.f;
    for (int ci = 0; ci < C_; ++ci) {
        __syncthreads();
        float4 r = *(const float4*)(hb + (size_t)ci * HW_ + t * 4);
        xs[t*4+0] = r.x; xs[t*4+1] = r.y; xs[t*4+2] = r.z; xs[t*4+3] = r.w;
        __syncthreads();
        const float x0v = xs[t], x1v = xs[t + 256], x2v = xs[t + 512], x3v = xs[t + 768];
        #pragma unroll
        for (int k = 0; k < 8; ++k) {
            float wv = ldq(wt, (long)(c0 + k) * C_ + ci, isf32);
            acc[k][0] += x0v * wv; acc[k][1] += x1v * wv;
            acc[k][2] += x2v * wv; acc[k][3] += x3v * wv;
        }
    }
    #pragma unroll
    for (int k = 0; k < 8; ++k) {
        float* o = g_tmp + (size_t)(b * C_ + c0 + k) * HW_;
        o[t] = acc[k][0]; o[t + 256] = acc[k][1];
        o[t + 512] = acc[k][2]; o[t + 768] = acc[k][3];
    }
    #pragma unroll
    for (int k = 0; k < 8; k += 2) {
        float sA  = acc[k][0] + acc[k][1] + acc[k][2] + acc[k][3];
        float s2A = acc[k][0]*acc[k][0] + acc[k][1]*acc[k][1]
                  + acc[k][2]*acc[k][2] + acc[k][3]*acc[k][3];
        float sB  = acc[k+1][0] + acc[k+1][1] + acc[k+1][2] + acc[k+1][3];
        float s2B = acc[k+1][0]*acc[k+1][0] + acc[k+1][1]*acc[k+1][1]
                  + acc[k+1][2]*acc[k+1][2] + acc[k+1][3]*acc[k+1][3];
        stats_ep2(red, t, sA, s2A, sB, s2B, c0 + k, c0 + k + 1, 6);
    }
}

// ---------------------------------------------------------------------------
// g_acc += sel * BN_slot(g_tmp)   (single-slot variant, used for sep conv)
// ---------------------------------------------------------------------------
__global__ __launch_bounds__(256)
void k_bnacc(const void* __restrict__ g, const void* __restrict__ bb,
             int slot, int selIdx) {
    float sv = g_sel[selIdx];
    if (sv == 0.0f) return;
    size_t idx = ((size_t)blockIdx.x * 256 + threadIdx.x) * 4;
    int c = (int)((idx >> 10) & (C_ - 1));
    int isf32 = g_isf32;
    float mean = g_stats[slot * 512 + c] * (1.0f / NPC_);
    float var  = g_stats[slot * 512 + 256 + c] * (1.0f / NPC_) - mean * mean;
    float rstd = rsqrtf(fmaxf(var, 0.f) + 1e-5f);
    float gv = ldq(g, c, isf32), bv = ldq(bb, c, isf32);
    float4 r = *(const float4*)(g_tmp + idx);
    float4 a = *(const float4*)(g_acc + idx);
    a.x += sv * ((r.x - mean) * rstd * gv + bv);
    a.y += sv * ((r.y - mean) * rstd * gv + bv);
    a.z += sv * ((r.z - mean) * rstd * gv + bv);
    a.w += sv * ((r.w - mean) * rstd * gv + bv);
    *(float4*)(g_acc + idx) = a;
}

// ---------------------------------------------------------------------------
// out = cast(g_acc)  (dtype-dual store)
// ---------------------------------------------------------------------------
__global__ __launch_bounds__(256)
void k_final(void* __restrict__ out) {
    size_t idx = ((size_t)blockIdx.x * 256 + threadIdx.x) * 4;
    float4 a = *(const float4*)(g_acc + idx);
    if (g_isf32) {
        *(float4*)((float*)out + idx) = a;
    } else {
        ushort4 o; o.x = f2u(a.x); o.y = f2u(a.y); o.z = f2u(a.z); o.w = f2u(a.w);
        *(ushort4*)((unsigned short*)out + idx) = o;
    }
}

// ---------------------------------------------------------------------------
extern "C" void kernel_launch(void* const* d_in, const int* in_sizes, int n_in,
                              void* d_out, int out_size, void* d_ws, size_t ws_size,
                              hipStream_t stream) {
    const void* x    = d_in[0];
    const void* aw   = d_in[1];
    const void* w_in = d_in[2];
    const void* g_in = d_in[3];
    const void* b_in = d_in[4];
    const void* w3   = d_in[5];
    const void* g3   = d_in[6];
    const void* b3   = d_in[7];
    const void* w5   = d_in[8];
    const void* g5   = d_in[9];
    const void* b5   = d_in[10];
    const void* wdw  = d_in[11];
    const void* wpw  = d_in[12];
    const void* gs   = d_in[13];
    const void* bs   = d_in[14];
    const void* wd   = d_in[15];
    const void* gd   = d_in[16];
    const void* bd   = d_in[17];
    const void* gmp  = d_in[18];
    const void* bmp  = d_in[19];
    const void* gap  = d_in[20];
    const void* bap  = d_in[21];

    dim3 Bk(256);
    dim3 Gfull(NB_);    // 16384 elementwise / per-(b,c) blocks
    dim3 Gc8(2048);     // COUT=8 1x1-conv blocks
    dim3 Gcv(8192);     // COUT=2 fused dense-conv blocks

    k_prep<<<dim3(1), Bk, 0, stream>>>(x, aw);

    // transition: 1x1 conv (COUT=8) -> fused BN+ReLU+skip-init
    k_trans<<<Gc8, Bk, 0, stream>>>(x, w_in);
    k_bnrelu_init<<<Gfull, Bk, 0, stream>>>(g_in, b_in);

    // ops 1+2: fused max/avg pool + fused BN-accumulate
    k_pool_fused<<<Gfull, Bk, 0, stream>>>();
    k_bnacc2<<<Gfull, Bk, 0, stream>>>(gmp, bmp, gap, bap);

    // ops 4+5+7: fused dense convs (shared staging/rows, COUT=2) + fused BN-acc
    k_conv_fused<<<Gcv, Bk, 0, stream>>>(w3, w5, wd);
    k_bnacc3<<<Gfull, Bk, 0, stream>>>(g3, b3, g5, b5, gd, bd);

    // op 6: sep_conv_3x3 (dw in-place on g_h -> pw COUT=8) + BN — LAST h user
    k_dw_inplace<<<Gfull, Bk, 0, stream>>>(wdw);
    k_pw<<<Gc8, Bk, 0, stream>>>(wpw);
    k_bnacc<<<Gfull, Bk, 0, stream>>>(gs, bs, 6, 6);

    k_final<<<Gfull, Bk, 0, stream>>>(d_out);
}

// Round 2
// 3721.050 us; speedup vs baseline: 1.0060x; 1.0060x over previous
//
#include <hip/hip_runtime.h>

#define CIN_  128
#define C_    256
#define HW_   1024      /* 32*32 */
#define NPC_  65536.0f  /* 64*1024 elements per channel for BN stats */
#define NB_   16384     /* 64 batches * 256 channels */

constexpr size_t NELEM = 16777216ull;   // 64*256*32*32

// ---- module-scope device scratch: one buffer per producer (no reuse hazards)
__device__ float g_sel[8];
__device__ float g_stats[8 * 512];      // per-slot: [0..255]=sum, [256..511]=sumsq
__device__ int   g_isf32;
__device__ float g_h[NELEM];            // relu(BN0(trans))
__device__ float g_c3[NELEM];           // conv3x3 out      (slot 4)
__device__ float g_c5[NELEM];           // conv5x5 out      (slot 5)
__device__ float g_cd[NELEM];           // dil conv out     (slot 7)
__device__ float g_pm[NELEM];           // maxpool out      (slot 1)
__device__ float g_pa[NELEM];           // avgpool out      (slot 2)
__device__ float g_pw[NELEM];           // pointwise out    (slot 6)
__device__ float g_dw[NELEM];           // trans tmp, then depthwise out

__device__ __forceinline__ float u2f(unsigned short u) {
    union { unsigned int i; float f; } x; x.i = ((unsigned int)u) << 16; return x.f;
}
__device__ __forceinline__ unsigned short f2u(float f) {
    union { float f; unsigned int i; } x; x.f = f;
    unsigned int r = x.i + 0x7fffu + ((x.i >> 16) & 1u);  // RNE
    return (unsigned short)(r >> 16);
}
__device__ __forceinline__ float ldq(const void* p, long i, int isf32) {
    return isf32 ? ((const float*)p)[i] : u2f(((const unsigned short*)p)[i]);
}

// ---------------------------------------------------------------------------
// prep: zero stats, detect input dtype, compute sel
// ---------------------------------------------------------------------------
__global__ void k_prep(const void* __restrict__ x, const void* __restrict__ aw) {
    __shared__ int flag_s;
    __shared__ float red[256];
    const int t = threadIdx.x;
    for (int i = t; i < 8 * 512; i += 256) g_stats[i] = 0.f;
    const unsigned short* xu = (const unsigned short*)x;
    int bad = 0;
    for (int i = t; i < 8192; i += 256) {
        unsigned int e = (xu[i] >> 7) & 0xFFu;
        if (e >= 0xC6u) ++bad;
    }
    red[t] = (float)bad;
    __syncthreads();
    for (int off = 128; off > 0; off >>= 1) {
        if (t < off) red[t] += red[t + off];
        __syncthreads();
    }
    if (t == 0) { flag_s = (red[0] > 4.0f) ? 1 : 0; g_isf32 = flag_s; }
    __syncthreads();
    const int isf32 = flag_s;
    if (t == 0) {
        float w[8];
        float mx = -1e30f;
        for (int i = 0; i < 8; ++i) { w[i] = ldq(aw, i, isf32); mx = fmaxf(mx, w[i]); }
        float s = 0.f;
        for (int i = 0; i < 8; ++i) { w[i] = expf(w[i] - mx); s += w[i]; }
        for (int i = 0; i < 8; ++i) w[i] /= s;
        float sv[8] = {0,0,0,0,0,0,0,0};
        bool used[8] = {false,false,false,false,false,false,false,false};
        for (int k = 0; k < 3; ++k) {          // top-3, first-index tie-break
            int bi = -1; float bv = -1.f;
            for (int i = 0; i < 8; ++i) if (!used[i] && w[i] > bv) { bv = w[i]; bi = i; }
            used[bi] = true; sv[bi] = bv;
        }
        float tot = 0.f;
        for (int i = 0; i < 8; ++i) { if (sv[i] < 0.01f) sv[i] = 0.f; tot += sv[i]; }
        tot = fmaxf(tot, 1e-12f);
        for (int i = 0; i < 8; ++i) g_sel[i] = sv[i] / tot;
    }
}

// ---------------------------------------------------------------------------
// stats epilogues: single-channel (red[512]) and channel-pair (red[1024])
// ---------------------------------------------------------------------------
__device__ __forceinline__ void stats_epilogue(float* red, float s, float s2,
                                               int t, int c, int slot) {
    __syncthreads();
    red[t] = s; red[t + 256] = s2;
    __syncthreads();
    for (int off = 128; off > 0; off >>= 1) {
        if (t < off) { red[t] += red[t + off]; red[t + 256] += red[t + 256 + off]; }
        __syncthreads();
    }
    if (t == 0) {
        atomicAdd(&g_stats[slot * 512 + c], red[0]);
        atomicAdd(&g_stats[slot * 512 + 256 + c], red[256]);
    }
}

__device__ __forceinline__ void stats_ep2(float* red, int t,
                                          float sA, float s2A, float sB, float s2B,
                                          int cA, int cB, int slot) {
    __syncthreads();
    red[t] = sA; red[t + 256] = s2A; red[t + 512] = sB; red[t + 768] = s2B;
    __syncthreads();
    for (int off = 128; off > 0; off >>= 1) {
        if (t < off) {
            red[t]       += red[t + off];
            red[t + 256] += red[t + 256 + off];
            red[t + 512] += red[t + 512 + off];
            red[t + 768] += red[t + 768 + off];
        }
        __syncthreads();
    }
    if (t == 0) {
        atomicAdd(&g_stats[slot * 512 + cA],       red[0]);
        atomicAdd(&g_stats[slot * 512 + 256 + cA], red[256]);
        atomicAdd(&g_stats[slot * 512 + cB],       red[512]);
        atomicAdd(&g_stats[slot * 512 + 256 + cB], red[768]);
    }
}

// ---------------------------------------------------------------------------
// transition 1x1 conv, COUT=8 per block -> g_dw, stats slot 0
// grid = 64 b * 32 cgroups = 2048
// ---------------------------------------------------------------------------
__global__ __launch_bounds__(256)
void k_trans(const void* __restrict__ xin, const void* __restrict__ wt) {
    __shared__ float xs[HW_];
    __shared__ float red[1024];
    const int t = threadIdx.x;
    const int c0 = (blockIdx.x & 31) * 8;
    const int b  = blockIdx.x >> 5;
    const int isf32 = g_isf32;
    float acc[8][4];
    #pragma unroll
    for (int k = 0; k < 8; ++k)
        #pragma unroll
        for (int j = 0; j < 4; ++j) acc[k][j] = 0.f;
    for (int ci = 0; ci < CIN_; ++ci) {
        __syncthreads();
        size_t vi = (size_t)(b * CIN_ + ci) * 256 + t;
        if (isf32) {
            float4 r = ((const float4*)xin)[vi];
            xs[t*4+0] = r.x; xs[t*4+1] = r.y; xs[t*4+2] = r.z; xs[t*4+3] = r.w;
        } else {
            ushort4 r = ((const ushort4*)xin)[vi];
            xs[t*4+0] = u2f(r.x); xs[t*4+1] = u2f(r.y);
            xs[t*4+2] = u2f(r.z); xs[t*4+3] = u2f(r.w);
        }
        __syncthreads();
        const float x0v = xs[t], x1v = xs[t + 256], x2v = xs[t + 512], x3v = xs[t + 768];
        #pragma unroll
        for (int k = 0; k < 8; ++k) {
            float wv = ldq(wt, (long)(c0 + k) * CIN_ + ci, isf32);
            acc[k][0] += x0v * wv; acc[k][1] += x1v * wv;
            acc[k][2] += x2v * wv; acc[k][3] += x3v * wv;
        }
    }
    #pragma unroll
    for (int k = 0; k < 8; ++k) {
        float* o = g_dw + (size_t)(b * C_ + c0 + k) * HW_;
        o[t] = acc[k][0]; o[t + 256] = acc[k][1];
        o[t + 512] = acc[k][2]; o[t + 768] = acc[k][3];
    }
    #pragma unroll
    for (int k = 0; k < 8; k += 2) {
        float sA  = acc[k][0] + acc[k][1] + acc[k][2] + acc[k][3];
        float s2A = acc[k][0]*acc[k][0] + acc[k][1]*acc[k][1]
                  + acc[k][2]*acc[k][2] + acc[k][3]*acc[k][3];
        float sB  = acc[k+1][0] + acc[k+1][1] + acc[k+1][2] + acc[k+1][3];
        float s2B = acc[k+1][0]*acc[k+1][0] + acc[k+1][1]*acc[k+1][1]
                  + acc[k+1][2]*acc[k+1][2] + acc[k+1][3]*acc[k+1][3];
        stats_ep2(red, t, sA, s2A, sB, s2B, c0 + k, c0 + k + 1, 0);
    }
}

// ---------------------------------------------------------------------------
// g_h = relu(BN0(g_dw))
// ---------------------------------------------------------------------------
__global__ __launch_bounds__(256)
void k_bnrelu(const void* __restrict__ g, const void* __restrict__ bb) {
    size_t idx = ((size_t)blockIdx.x * 256 + threadIdx.x) * 4;
    int c = (int)((idx >> 10) & (C_ - 1));
    int isf32 = g_isf32;
    float mean = g_stats[c] * (1.0f / NPC_);
    float var  = g_stats[256 + c] * (1.0f / NPC_) - mean * mean;
    float rstd = rsqrtf(fmaxf(var, 0.f) + 1e-5f);
    float gv = ldq(g, c, isf32), bv = ldq(bb, c, isf32);
    float4 r = *(const float4*)(g_dw + idx);
    float4 h;
    h.x = fmaxf(0.f, (r.x - mean) * rstd * gv + bv);
    h.y = fmaxf(0.f, (r.y - mean) * rstd * gv + bv);
    h.z = fmaxf(0.f, (r.z - mean) * rstd * gv + bv);
    h.w = fmaxf(0.f, (r.w - mean) * rstd * gv + bv);
    *(float4*)(g_h + idx) = h;
}

// ---------------------------------------------------------------------------
// fused max+avg 3x3 pooling on g_h: max -> g_pm (slot 1), avg -> g_pa (slot 2)
// stride-33 LDS (~2-way, free per m136)
// ---------------------------------------------------------------------------
__global__ __launch_bounds__(256)
void k_pool_fused() {
    const float s1 = g_sel[1], s2 = g_sel[2];
    if (s1 == 0.f && s2 == 0.f) return;
    __shared__ float xs[34 * 33];
    __shared__ float red[512];
    const int t = threadIdx.x;
    const int c = blockIdx.x & (C_ - 1);
    const int y  = t >> 3;
    const int x0 = (t & 7) * 4;
    const float* hp = g_h + (size_t)blockIdx.x * HW_;
    float4 r = *(const float4*)(hp + t * 4);
    float* xw = xs + y * 33 + x0;
    xw[0] = r.x; xw[1] = r.y; xw[2] = r.z; xw[3] = r.w;
    __syncthreads();
    float mx[4] = {0.f, 0.f, 0.f, 0.f};       // h >= 0 post-ReLU; matches padded max
    float sm[4] = {0.f, 0.f, 0.f, 0.f};
    #pragma unroll
    for (int ky = 0; ky < 3; ++ky) {
        int iy = y + ky - 1;
        if (iy < 0 || iy >= 32) continue;
        float row[6];
        #pragma unroll
        for (int i = 0; i < 6; ++i) {
            int ix = x0 + i - 1;
            row[i] = (ix >= 0 && ix < 32) ? xs[iy * 33 + ix] : 0.0f;
        }
        #pragma unroll
        for (int kx = 0; kx < 3; ++kx)
            #pragma unroll
            for (int j = 0; j < 4; ++j) {
                mx[j] = fmaxf(mx[j], row[j + kx]);
                sm[j] += row[j + kx];
            }
    }
    #pragma unroll
    for (int j = 0; j < 4; ++j) sm[j] *= (1.0f / 9.0f);
    const size_t ob = (size_t)blockIdx.x * HW_ + y * 32 + x0;
    if (s1 != 0.f) {
        float* o = g_pm + ob;
        o[0] = mx[0]; o[1] = mx[1]; o[2] = mx[2]; o[3] = mx[3];
        stats_epilogue(red, mx[0]+mx[1]+mx[2]+mx[3],
                       mx[0]*mx[0]+mx[1]*mx[1]+mx[2]*mx[2]+mx[3]*mx[3], t, c, 1);
    }
    if (s2 != 0.f) {
        float* o = g_pa + ob;
        o[0] = sm[0]; o[1] = sm[1]; o[2] = sm[2]; o[3] = sm[3];
        stats_epilogue(red, sm[0]+sm[1]+sm[2]+sm[3],
                       sm[0]*sm[0]+sm[1]*sm[1]+sm[2]*sm[2]+sm[3]*sm[3], t, c, 2);
    }
}

// ---------------------------------------------------------------------------
// FUSED dense convs, COUT=4, double-buffered LDS, 1 barrier/ci, load-early:
// conv3x3 (slot 4 -> g_c3), conv5x5 (slot 5 -> g_c5), dil3x3 (slot 7 -> g_cd).
// grid = 64 b * 64 cg = 4096.  Per ci: 688 FMA vs 40 LDS reads vs 1 glb load.
// ---------------------------------------------------------------------------
__global__ __launch_bounds__(256)
void k_conv_fused(const void* __restrict__ w3p, const void* __restrict__ w5p,
                  const void* __restrict__ wdp) {
    const bool h3 = (g_sel[4] != 0.f), h5 = (g_sel[5] != 0.f), hd = (g_sel[7] != 0.f);
    if (!h3 && !h5 && !hd) return;
    __shared__ float xs[2][34 * 33];
    __shared__ float red[1024];
    const int t  = threadIdx.x;
    const int c0 = (blockIdx.x & 63) * 4;
    const int b  = blockIdx.x >> 6;
    const int y  = t >> 3;
    const int x0 = (t & 7) * 4;
    const int isf32 = g_isf32;
    const float* hb = g_h + (size_t)b * C_ * HW_;
    // per-thread column offsets/masks, hoisted out of the ci loop
    int xoff[8]; int xok[8];
    #pragma unroll
    for (int i = 0; i < 8; ++i) {
        int ix = x0 + i - 2;
        xok[i]  = (ix >= 0 && ix < 32) ? 1 : 0;
        xoff[i] = ix < 0 ? 0 : (ix > 31 ? 31 : ix);
    }
    long wb3[4], wb5[4];
    #pragma unroll
    for (int u = 0; u < 4; ++u) {
        wb3[u] = (long)(c0 + u) * C_ * 9;
        wb5[u] = (long)(c0 + u) * C_ * 25;
    }
    float a3[4][4], a5[4][4], ad[4][4];
    #pragma unroll
    for (int u = 0; u < 4; ++u)
        #pragma unroll
        for (int j = 0; j < 4; ++j) { a3[u][j] = 0.f; a5[u][j] = 0.f; ad[u][j] = 0.f; }

    // prologue: stage ci=0
    {
        float4 r0 = *(const float4*)(hb + t * 4);
        float* xw = xs[0] + y * 33 + x0;
        xw[0] = r0.x; xw[1] = r0.y; xw[2] = r0.z; xw[3] = r0.w;
    }
    __syncthreads();
    int cur = 0;

    for (int ci = 0; ci < C_; ++ci) {
        // issue next-channel load EARLY (latency hides under the 688-FMA body)
        float4 rN = {0.f, 0.f, 0.f, 0.f};
        if (ci + 1 < C_)
            rN = *(const float4*)(hb + (size_t)(ci + 1) * HW_ + t * 4);
        const float* xsc = xs[cur];
        #pragma unroll
        for (int io = 0; io < 5; ++io) {
            const int iy  = y + io - 2;
            const int yok = (iy >= 0 && iy < 32) ? 1 : 0;
            const int yb  = (iy < 0 ? 0 : (iy > 31 ? 31 : iy)) * 33;
            float row[8];
            #pragma unroll
            for (int i = 0; i < 8; ++i) {
                float v = xsc[yb + xoff[i]];         // clamped addr: always in-bounds
                row[i] = (yok & xok[i]) ? v : 0.f;   // zero-pad semantics
            }
            if (h5) {
                #pragma unroll
                for (int kx = 0; kx < 5; ++kx) {
                    #pragma unroll
                    for (int u = 0; u < 4; ++u) {
                        float w = ldq(w5p, wb5[u] + (long)ci * 25 + io * 5 + kx, isf32);
                        #pragma unroll
                        for (int j = 0; j < 4; ++j) a5[u][j] += row[j + kx] * w;
                    }
                }
            }
            if (h3 && io >= 1 && io <= 3) {
                const int ky = io - 1;
                #pragma unroll
                for (int kx = 0; kx < 3; ++kx) {
                    #pragma unroll
                    for (int u = 0; u < 4; ++u) {
                        float w = ldq(w3p, wb3[u] + (long)ci * 9 + ky * 3 + kx, isf32);
                        #pragma unroll
                        for (int j = 0; j < 4; ++j) a3[u][j] += row[j + kx + 1] * w;
                    }
                }
            }
            if (hd && (io & 1) == 0) {
                const int ky = io >> 1;
                #pragma unroll
                for (int kx = 0; kx < 3; ++kx) {
                    #pragma unroll
                    for (int u = 0; u < 4; ++u) {
                        float w = ldq(wdp, wb3[u] + (long)ci * 9 + ky * 3 + kx, isf32);
                        #pragma unroll
                        for (int j = 0; j < 4; ++j) ad[u][j] += row[j + 2 * kx] * w;
                    }
                }
            }
        }
        // write-late into the other buffer; single barrier per ci suffices:
        // reads of buf[cur^1] (iter ci-1) are separated from these writes by
        // the barrier at the end of iter ci-1.
        if (ci + 1 < C_) {
            float* xw = xs[cur ^ 1] + y * 33 + x0;
            xw[0] = rN.x; xw[1] = rN.y; xw[2] = rN.z; xw[3] = rN.w;
        }
        __syncthreads();
        cur ^= 1;
    }

    size_t ob[4];
    #pragma unroll
    for (int u = 0; u < 4; ++u)
        ob[u] = (size_t)(b * C_ + c0 + u) * HW_ + y * 32 + x0;

    if (h3) {
        #pragma unroll
        for (int u = 0; u < 4; ++u) {
            float4 o; o.x = a3[u][0]; o.y = a3[u][1]; o.z = a3[u][2]; o.w = a3[u][3];
            *(float4*)(g_c3 + ob[u]) = o;
        }
        #pragma unroll
        for (int u = 0; u < 4; u += 2)
            stats_ep2(red, t,
                a3[u][0]+a3[u][1]+a3[u][2]+a3[u][3],
                a3[u][0]*a3[u][0]+a3[u][1]*a3[u][1]+a3[u][2]*a3[u][2]+a3[u][3]*a3[u][3],
                a3[u+1][0]+a3[u+1][1]+a3[u+1][2]+a3[u+1][3],
                a3[u+1][0]*a3[u+1][0]+a3[u+1][1]*a3[u+1][1]+a3[u+1][2]*a3[u+1][2]+a3[u+1][3]*a3[u+1][3],
                c0 + u, c0 + u + 1, 4);
    }
    if (h5) {
        #pragma unroll
        for (int u = 0; u < 4; ++u) {
            float4 o; o.x = a5[u][0]; o.y = a5[u][1]; o.z = a5[u][2]; o.w = a5[u][3];
            *(float4*)(g_c5 + ob[u]) = o;
        }
        #pragma unroll
        for (int u = 0; u < 4; u += 2)
            stats_ep2(red, t,
                a5[u][0]+a5[u][1]+a5[u][2]+a5[u][3],
                a5[u][0]*a5[u][0]+a5[u][1]*a5[u][1]+a5[u][2]*a5[u][2]+a5[u][3]*a5[u][3],
                a5[u+1][0]+a5[u+1][1]+a5[u+1][2]+a5[u+1][3],
                a5[u+1][0]*a5[u+1][0]+a5[u+1][1]*a5[u+1][1]+a5[u+1][2]*a5[u+1][2]+a5[u+1][3]*a5[u+1][3],
                c0 + u, c0 + u + 1, 5);
    }
    if (hd) {
        #pragma unroll
        for (int u = 0; u < 4; ++u) {
            float4 o; o.x = ad[u][0]; o.y = ad[u][1]; o.z = ad[u][2]; o.w = ad[u][3];
            *(float4*)(g_cd + ob[u]) = o;
        }
        #pragma unroll
        for (int u = 0; u < 4; u += 2)
            stats_ep2(red, t,
                ad[u][0]+ad[u][1]+ad[u][2]+ad[u][3],
                ad[u][0]*ad[u][0]+ad[u][1]*ad[u][1]+ad[u][2]*ad[u][2]+ad[u][3]*ad[u][3],
                ad[u+1][0]+ad[u+1][1]+ad[u+1][2]+ad[u+1][3],
                ad[u+1][0]*ad[u+1][0]+ad[u+1][1]*ad[u+1][1]+ad[u+1][2]*ad[u+1][2]+ad[u+1][3]*ad[u+1][3],
                c0 + u, c0 + u + 1, 7);
    }
}

// ---------------------------------------------------------------------------
// depthwise 3x3: g_h -> g_dw (g_h preserved for the skip term in k_final_all)
// ---------------------------------------------------------------------------
__global__ __launch_bounds__(256)
void k_dw(const void* __restrict__ wt) {
    if (g_sel[6] == 0.0f) return;
    __shared__ float xs[34 * 33];
    const int t = threadIdx.x;
    const int c = blockIdx.x & (C_ - 1);
    const int y  = t >> 3;
    const int x0 = (t & 7) * 4;
    const int isf32 = g_isf32;
    const float* hp = g_h + (size_t)blockIdx.x * HW_;
    float4 r = *(const float4*)(hp + t * 4);
    float* xw = xs + y * 33 + x0;
    xw[0] = r.x; xw[1] = r.y; xw[2] = r.z; xw[3] = r.w;
    __syncthreads();
    float wv[9];
    #pragma unroll
    for (int k = 0; k < 9; ++k) wv[k] = ldq(wt, (long)c * 9 + k, isf32);
    float acc[4] = {0.f, 0.f, 0.f, 0.f};
    #pragma unroll
    for (int ky = 0; ky < 3; ++ky) {
        int iy = y + ky - 1;
        if (iy < 0 || iy >= 32) continue;
        float row[6];
        #pragma unroll
        for (int i = 0; i < 6; ++i) {
            int ix = x0 + i - 1;
            row[i] = (ix >= 0 && ix < 32) ? xs[iy * 33 + ix] : 0.0f;
        }
        #pragma unroll
        for (int kx = 0; kx < 3; ++kx)
            #pragma unroll
            for (int j = 0; j < 4; ++j)
                acc[j] += row[j + kx] * wv[ky * 3 + kx];
    }
    float* o = g_dw + (size_t)blockIdx.x * HW_ + y * 32 + x0;
    o[0] = acc[0]; o[1] = acc[1]; o[2] = acc[2]; o[3] = acc[3];
}

// ---------------------------------------------------------------------------
// pointwise 1x1 conv on g_dw, COUT=8 -> g_pw + fused stats slot 6
// grid = 64 b * 32 cgroups = 2048
// ---------------------------------------------------------------------------
__global__ __launch_bounds__(256)
void k_pw(const void* __restrict__ wt) {
    if (g_sel[6] == 0.0f) return;
    __shared__ float xs[HW_];
    __shared__ float red[1024];
    const int t = threadIdx.x;
    const int c0 = (blockIdx.x & 31) * 8;
    const int b  = blockIdx.x >> 5;
    const int isf32 = g_isf32;
    const float* hb = g_dw + (size_t)b * C_ * HW_;
    float acc[8][4];
    #pragma unroll
    for (int k = 0; k < 8; ++k)
        #pragma unroll
        for (int j = 0; j < 4; ++j) acc[k][j] = 0.f;
    for (int ci = 0; ci < C_; ++ci) {
        __syncthreads();
        float4 r = *(const float4*)(hb + (size_t)ci * HW_ + t * 4);
        xs[t*4+0] = r.x; xs[t*4+1] = r.y; xs[t*4+2] = r.z; xs[t*4+3] = r.w;
        __syncthreads();
        const float x0v = xs[t], x1v = xs[t + 256], x2v = xs[t + 512], x3v = xs[t + 768];
        #pragma unroll
        for (int k = 0; k < 8; ++k) {
            float wv = ldq(wt, (long)(c0 + k) * C_ + ci, isf32);
            acc[k][0] += x0v * wv; acc[k][1] += x1v * wv;
            acc[k][2] += x2v * wv; acc[k][3] += x3v * wv;
        }
    }
    #pragma unroll
    for (int k = 0; k < 8; ++k) {
        float* o = g_pw + (size_t)(b * C_ + c0 + k) * HW_;
        o[t] = acc[k][0]; o[t + 256] = acc[k][1];
        o[t + 512] = acc[k][2]; o[t + 768] = acc[k][3];
    }
    #pragma unroll
    for (int k = 0; k < 8; k += 2) {
        float sA  = acc[k][0] + acc[k][1] + acc[k][2] + acc[k][3];
        float s2A = acc[k][0]*acc[k][0] + acc[k][1]*acc[k][1]
                  + acc[k][2]*acc[k][2] + acc[k][3]*acc[k][3];
        float sB  = acc[k+1][0] + acc[k+1][1] + acc[k+1][2] + acc[k+1][3];
        float s2B = acc[k+1][0]*acc[k+1][0] + acc[k+1][1]*acc[k+1][1]
                  + acc[k+1][2]*acc[k+1][2] + acc[k+1][3]*acc[k+1][3];
        stats_ep2(red, t, sA, s2A, sB, s2B, c0 + k, c0 + k + 1, 6);
    }
}

// ---------------------------------------------------------------------------
// single fused epilogue: out = sel3*h + Σ sel_k * BN_k(buf_k), dtype-dual
// ---------------------------------------------------------------------------
__device__ __forceinline__ void bn_term(float4& o, const float* buf, size_t idx,
                                        int c, int slot, float sv,
                                        const void* g, const void* bb, int isf32) {
    float mean = g_stats[slot * 512 + c] * (1.0f / NPC_);
    float var  = g_stats[slot * 512 + 256 + c] * (1.0f / NPC_) - mean * mean;
    float rstd = rsqrtf(fmaxf(var, 0.f) + 1e-5f);
    float gv = ldq(g, c, isf32), bv = ldq(bb, c, isf32);
    float4 r = *(const float4*)(buf + idx);
    o.x += sv * ((r.x - mean) * rstd * gv + bv);
    o.y += sv * ((r.y - mean) * rstd * gv + bv);
    o.z += sv * ((r.z - mean) * rstd * gv + bv);
    o.w += sv * ((r.w - mean) * rstd * gv + bv);
}

__global__ __launch_bounds__(256)
void k_final_all(void* __restrict__ out,
                 const void* __restrict__ gmp, const void* __restrict__ bmp,
                 const void* __restrict__ gap, const void* __restrict__ bap,
                 const void* __restrict__ g3,  const void* __restrict__ b3,
                 const void* __restrict__ g5,  const void* __restrict__ b5,
                 const void* __restrict__ gs,  const void* __restrict__ bs,
                 const void* __restrict__ gd,  const void* __restrict__ bd) {
    size_t idx = ((size_t)blockIdx.x * 256 + threadIdx.x) * 4;
    int c = (int)((idx >> 10) & (C_ - 1));
    int isf32 = g_isf32;
    float4 o = {0.f, 0.f, 0.f, 0.f};
    float s3 = g_sel[3];
    if (s3 != 0.f) {
        float4 h = *(const float4*)(g_h + idx);
        o.x = s3 * h.x; o.y = s3 * h.y; o.z = s3 * h.z; o.w = s3 * h.w;
    }
    float sv;
    if ((sv = g_sel[1]) != 0.f) bn_term(o, g_pm, idx, c, 1, sv, gmp, bmp, isf32);
    if ((sv = g_sel[2]) != 0.f) bn_term(o, g_pa, idx, c, 2, sv, gap, bap, isf32);
    if ((sv = g_sel[4]) != 0.f) bn_term(o, g_c3, idx, c, 4, sv, g3,  b3,  isf32);
    if ((sv = g_sel[5]) != 0.f) bn_term(o, g_c5, idx, c, 5, sv, g5,  b5,  isf32);
    if ((sv = g_sel[6]) != 0.f) bn_term(o, g_pw, idx, c, 6, sv, gs,  bs,  isf32);
    if ((sv = g_sel[7]) != 0.f) bn_term(o, g_cd, idx, c, 7, sv, gd,  bd,  isf32);
    if (isf32) {
        *(float4*)((float*)out + idx) = o;
    } else {
        ushort4 u; u.x = f2u(o.x); u.y = f2u(o.y); u.z = f2u(o.z); u.w = f2u(o.w);
        *(ushort4*)((unsigned short*)out + idx) = u;
    }
}

// ---------------------------------------------------------------------------
extern "C" void kernel_launch(void* const* d_in, const int* in_sizes, int n_in,
                              void* d_out, int out_size, void* d_ws, size_t ws_size,
                              hipStream_t stream) {
    const void* x    = d_in[0];
    const void* aw   = d_in[1];
    const void* w_in = d_in[2];
    const void* g_in = d_in[3];
    const void* b_in = d_in[4];
    const void* w3   = d_in[5];
    const void* g3   = d_in[6];
    const void* b3   = d_in[7];
    const void* w5   = d_in[8];
    const void* g5   = d_in[9];
    const void* b5   = d_in[10];
    const void* wdw  = d_in[11];
    const void* wpw  = d_in[12];
    const void* gs   = d_in[13];
    const void* bs   = d_in[14];
    const void* wd   = d_in[15];
    const void* gd   = d_in[16];
    const void* bd   = d_in[17];
    const void* gmp  = d_in[18];
    const void* bmp  = d_in[19];
    const void* gap  = d_in[20];
    const void* bap  = d_in[21];

    dim3 Bk(256);
    dim3 Gfull(NB_);    // 16384 elementwise / per-(b,c) blocks
    dim3 Gc8(2048);     // COUT=8 1x1-conv blocks
    dim3 Gcv(4096);     // COUT=4 fused dense-conv blocks

    k_prep<<<dim3(1), Bk, 0, stream>>>(x, aw);

    // transition: 1x1 conv (COUT=8) -> g_dw; then g_h = relu(BN0(g_dw))
    k_trans<<<Gc8, Bk, 0, stream>>>(x, w_in);
    k_bnrelu<<<Gfull, Bk, 0, stream>>>(g_in, b_in);

    // ops 1+2: fused max/avg pool -> g_pm/g_pa
    k_pool_fused<<<Gfull, Bk, 0, stream>>>();

    // ops 4+5+7: fused dense convs (COUT=4, dbuf, 1 barrier/ci) -> g_c3/g_c5/g_cd
    k_conv_fused<<<Gcv, Bk, 0, stream>>>(w3, w5, wd);

    // op 6: sep_conv_3x3: dw (g_h -> g_dw), pw (g_dw -> g_pw)
    k_dw<<<Gfull, Bk, 0, stream>>>(wdw);
    k_pw<<<Gc8, Bk, 0, stream>>>(wpw);

    // single fused epilogue: out = sel3*h + sum sel_k*BN_k(buf_k)
    k_final_all<<<Gfull, Bk, 0, stream>>>(d_out,
        gmp, bmp, gap, bap, g3, b3, g5, b5, gs, bs, gd, bd);
}

// Round 4
// 1746.295 us; speedup vs baseline: 2.1435x; 2.1308x over previous
//
#include <hip/hip_runtime.h>

#define CIN_  128
#define C_    256
#define HW_   1024      /* 32*32 */
#define NPC_  65536.0f  /* 64*1024 elements per channel for BN stats */
#define NB_   16384     /* 64 batches * 256 channels */

constexpr size_t NELEM = 16777216ull;   // 64*256*32*32

// ---- module-scope device scratch: one buffer per producer (no reuse hazards)
__device__ float g_sel[8];
__device__ float g_stats[8 * 512];      // per-slot: [0..255]=sum, [256..511]=sumsq
__device__ int   g_isf32;
__device__ float g_h[NELEM];            // relu(BN0(trans))
__device__ float g_c3[NELEM];           // conv3x3 out      (slot 4)
__device__ float g_c5[NELEM];           // conv5x5 out      (slot 5)
__device__ float g_cd[NELEM];           // dil conv out     (slot 7)
__device__ float g_pm[NELEM];           // maxpool out      (slot 1)
__device__ float g_pa[NELEM];           // avgpool out      (slot 2)
__device__ float g_pw[NELEM];           // pointwise out    (slot 6)
__device__ float g_dw[NELEM];           // trans tmp, then depthwise out

// ---- prepass-converted f32 weights, packed for float4 loads ----------------
// g_w5f: [cg=64][ci=256][tap=25][u=4]  (co = cg*4+u)
// g_w3f/g_wdf: [cg=64][ci=256][tap=9][u=4]
// g_wtf: [cg=32][ci=128][u=8]          (co = cg*8+u, transition conv)
__device__ float g_w5f[64 * 256 * 25 * 4];
__device__ float g_w3f[64 * 256 * 9 * 4];
__device__ float g_wdf[64 * 256 * 9 * 4];
__device__ float g_wtf[32 * 128 * 8];

__device__ __forceinline__ float u2f(unsigned short u) {
    union { unsigned int i; float f; } x; x.i = ((unsigned int)u) << 16; return x.f;
}
__device__ __forceinline__ unsigned short f2u(float f) {
    union { float f; unsigned int i; } x; x.f = f;
    unsigned int r = x.i + 0x7fffu + ((x.i >> 16) & 1u);  // RNE
    return (unsigned short)(r >> 16);
}
__device__ __forceinline__ float ldq(const void* p, long i, int isf32) {
    return isf32 ? ((const float*)p)[i] : u2f(((const unsigned short*)p)[i]);
}

// ---------------------------------------------------------------------------
// prep: zero stats, detect input dtype, compute sel
// ---------------------------------------------------------------------------
__global__ void k_prep(const void* __restrict__ x, const void* __restrict__ aw) {
    __shared__ int flag_s;
    __shared__ float red[256];
    const int t = threadIdx.x;
    for (int i = t; i < 8 * 512; i += 256) g_stats[i] = 0.f;
    const unsigned short* xu = (const unsigned short*)x;
    int bad = 0;
    for (int i = t; i < 8192; i += 256) {
        unsigned int e = (xu[i] >> 7) & 0xFFu;
        if (e >= 0xC6u) ++bad;
    }
    red[t] = (float)bad;
    __syncthreads();
    for (int off = 128; off > 0; off >>= 1) {
        if (t < off) red[t] += red[t + off];
        __syncthreads();
    }
    if (t == 0) { flag_s = (red[0] > 4.0f) ? 1 : 0; g_isf32 = flag_s; }
    __syncthreads();
    const int isf32 = flag_s;
    if (t == 0) {
        float w[8];
        float mx = -1e30f;
        for (int i = 0; i < 8; ++i) { w[i] = ldq(aw, i, isf32); mx = fmaxf(mx, w[i]); }
        float s = 0.f;
        for (int i = 0; i < 8; ++i) { w[i] = expf(w[i] - mx); s += w[i]; }
        for (int i = 0; i < 8; ++i) w[i] /= s;
        float sv[8] = {0,0,0,0,0,0,0,0};
        bool used[8] = {false,false,false,false,false,false,false,false};
        for (int k = 0; k < 3; ++k) {          // top-3, first-index tie-break
            int bi = -1; float bv = -1.f;
            for (int i = 0; i < 8; ++i) if (!used[i] && w[i] > bv) { bv = w[i]; bi = i; }
            used[bi] = true; sv[bi] = bv;
        }
        float tot = 0.f;
        for (int i = 0; i < 8; ++i) { if (sv[i] < 0.01f) sv[i] = 0.f; tot += sv[i]; }
        tot = fmaxf(tot, 1e-12f);
        for (int i = 0; i < 8; ++i) g_sel[i] = sv[i] / tot;
    }
}

// ---------------------------------------------------------------------------
// weight prepass: convert to f32, repack co-fastest (float4 per (ci,tap)).
// grid = 64 blocks (cg). Runs after k_prep (needs g_isf32).
// ---------------------------------------------------------------------------
__global__ __launch_bounds__(256)
void k_wconv(const void* __restrict__ w3, const void* __restrict__ w5,
             const void* __restrict__ wd, const void* __restrict__ wi) {
    const int cg = blockIdx.x;
    const int t  = threadIdx.x;
    const int isf32 = g_isf32;
    // w5: out o = ((ci*25+tap)*4+u)
    for (int o = t; o < 25600; o += 256) {
        int u = o & 3, r = o >> 2, tap = r % 25, ci = r / 25;
        g_w5f[(size_t)cg * 25600 + o] =
            ldq(w5, ((long)(cg * 4 + u) * C_ + ci) * 25 + tap, isf32);
    }
    // w3 / wd: out o = ((ci*9+tap)*4+u)
    for (int o = t; o < 9216; o += 256) {
        int u = o & 3, r = o >> 2, tap = r % 9, ci = r / 9;
        long ii = ((long)(cg * 4 + u) * C_ + ci) * 9 + tap;
        g_w3f[(size_t)cg * 9216 + o] = ldq(w3, ii, isf32);
        g_wdf[(size_t)cg * 9216 + o] = ldq(wd, ii, isf32);
    }
    // transition weights: [cg=32][ci=128][u=8]
    if (cg < 32) {
        for (int o = t; o < 1024; o += 256) {
            int u = o & 7, ci = o >> 3;
            g_wtf[cg * 1024 + o] = ldq(wi, (long)(cg * 8 + u) * CIN_ + ci, isf32);
        }
    }
}

// ---------------------------------------------------------------------------
// stats epilogues: single-channel (red[512]) and channel-pair (red[1024])
// ---------------------------------------------------------------------------
__device__ __forceinline__ void stats_epilogue(float* red, float s, float s2,
                                               int t, int c, int slot) {
    __syncthreads();
    red[t] = s; red[t + 256] = s2;
    __syncthreads();
    for (int off = 128; off > 0; off >>= 1) {
        if (t < off) { red[t] += red[t + off]; red[t + 256] += red[t + 256 + off]; }
        __syncthreads();
    }
    if (t == 0) {
        atomicAdd(&g_stats[slot * 512 + c], red[0]);
        atomicAdd(&g_stats[slot * 512 + 256 + c], red[256]);
    }
}

__device__ __forceinline__ void stats_ep2(float* red, int t,
                                          float sA, float s2A, float sB, float s2B,
                                          int cA, int cB, int slot) {
    __syncthreads();
    red[t] = sA; red[t + 256] = s2A; red[t + 512] = sB; red[t + 768] = s2B;
    __syncthreads();
    for (int off = 128; off > 0; off >>= 1) {
        if (t < off) {
            red[t]       += red[t + off];
            red[t + 256] += red[t + 256 + off];
            red[t + 512] += red[t + 512 + off];
            red[t + 768] += red[t + 768 + off];
        }
        __syncthreads();
    }
    if (t == 0) {
        atomicAdd(&g_stats[slot * 512 + cA],       red[0]);
        atomicAdd(&g_stats[slot * 512 + 256 + cA], red[256]);
        atomicAdd(&g_stats[slot * 512 + cB],       red[512]);
        atomicAdd(&g_stats[slot * 512 + 256 + cB], red[768]);
    }
}

// ---------------------------------------------------------------------------
// transition 1x1 conv, COUT=8, f32 float4 weights, dbuf 1-barrier pipeline
// -> g_dw, stats slot 0. grid = 64 b * 32 cgroups = 2048
// ---------------------------------------------------------------------------
__global__ __launch_bounds__(256)
void k_trans(const void* __restrict__ xin) {
    __shared__ float xs[2][HW_];
    __shared__ float red[1024];
    const int t  = threadIdx.x;
    const int cg = blockIdx.x & 31;
    const int c0 = cg * 8;
    const int b  = blockIdx.x >> 5;
    const int isf32 = g_isf32;
    const float* wb = g_wtf + cg * 1024;
    float acc[8][4];
    #pragma unroll
    for (int k = 0; k < 8; ++k)
        #pragma unroll
        for (int j = 0; j < 4; ++j) acc[k][j] = 0.f;

    // prologue: stage ci=0
    {
        size_t vi = (size_t)(b * CIN_) * 256 + t;
        float4 r0;
        if (isf32) r0 = ((const float4*)xin)[vi];
        else {
            ushort4 r = ((const ushort4*)xin)[vi];
            r0.x = u2f(r.x); r0.y = u2f(r.y); r0.z = u2f(r.z); r0.w = u2f(r.w);
        }
        xs[0][t*4+0] = r0.x; xs[0][t*4+1] = r0.y;
        xs[0][t*4+2] = r0.z; xs[0][t*4+3] = r0.w;
    }
    __syncthreads();
    int cur = 0;
    for (int ci = 0; ci < CIN_; ++ci) {
        float4 rN = {0.f, 0.f, 0.f, 0.f};
        if (ci + 1 < CIN_) {
            size_t vi = (size_t)(b * CIN_ + ci + 1) * 256 + t;
            if (isf32) rN = ((const float4*)xin)[vi];
            else {
                ushort4 r = ((const ushort4*)xin)[vi];
                rN.x = u2f(r.x); rN.y = u2f(r.y); rN.z = u2f(r.z); rN.w = u2f(r.w);
            }
        }
        const float x0v = xs[cur][t      ], x1v = xs[cur][t + 256];
        const float x2v = xs[cur][t + 512], x3v = xs[cur][t + 768];
        float4 wq0 = *(const float4*)(wb + ci * 8);
        float4 wq1 = *(const float4*)(wb + ci * 8 + 4);
        acc[0][0] += x0v*wq0.x; acc[0][1] += x1v*wq0.x; acc[0][2] += x2v*wq0.x; acc[0][3] += x3v*wq0.x;
        acc[1][0] += x0v*wq0.y; acc[1][1] += x1v*wq0.y; acc[1][2] += x2v*wq0.y; acc[1][3] += x3v*wq0.y;
        acc[2][0] += x0v*wq0.z; acc[2][1] += x1v*wq0.z; acc[2][2] += x2v*wq0.z; acc[2][3] += x3v*wq0.z;
        acc[3][0] += x0v*wq0.w; acc[3][1] += x1v*wq0.w; acc[3][2] += x2v*wq0.w; acc[3][3] += x3v*wq0.w;
        acc[4][0] += x0v*wq1.x; acc[4][1] += x1v*wq1.x; acc[4][2] += x2v*wq1.x; acc[4][3] += x3v*wq1.x;
        acc[5][0] += x0v*wq1.y; acc[5][1] += x1v*wq1.y; acc[5][2] += x2v*wq1.y; acc[5][3] += x3v*wq1.y;
        acc[6][0] += x0v*wq1.z; acc[6][1] += x1v*wq1.z; acc[6][2] += x2v*wq1.z; acc[6][3] += x3v*wq1.z;
        acc[7][0] += x0v*wq1.w; acc[7][1] += x1v*wq1.w; acc[7][2] += x2v*wq1.w; acc[7][3] += x3v*wq1.w;
        if (ci + 1 < CIN_) {
            float* xw = xs[cur ^ 1] + t * 4;
            xw[0] = rN.x; xw[1] = rN.y; xw[2] = rN.z; xw[3] = rN.w;
        }
        __syncthreads();
        cur ^= 1;
    }
    #pragma unroll
    for (int k = 0; k < 8; ++k) {
        float* o = g_dw + (size_t)(b * C_ + c0 + k) * HW_;
        o[t] = acc[k][0]; o[t + 256] = acc[k][1];
        o[t + 512] = acc[k][2]; o[t + 768] = acc[k][3];
    }
    #pragma unroll
    for (int k = 0; k < 8; k += 2) {
        float sA  = acc[k][0] + acc[k][1] + acc[k][2] + acc[k][3];
        float s2A = acc[k][0]*acc[k][0] + acc[k][1]*acc[k][1]
                  + acc[k][2]*acc[k][2] + acc[k][3]*acc[k][3];
        float sB  = acc[k+1][0] + acc[k+1][1] + acc[k+1][2] + acc[k+1][3];
        float s2B = acc[k+1][0]*acc[k+1][0] + acc[k+1][1]*acc[k+1][1]
                  + acc[k+1][2]*acc[k+1][2] + acc[k+1][3]*acc[k+1][3];
        stats_ep2(red, t, sA, s2A, sB, s2B, c0 + k, c0 + k + 1, 0);
    }
}

// ---------------------------------------------------------------------------
// g_h = relu(BN0(g_dw))
// ---------------------------------------------------------------------------
__global__ __launch_bounds__(256)
void k_bnrelu(const void* __restrict__ g, const void* __restrict__ bb) {
    size_t idx = ((size_t)blockIdx.x * 256 + threadIdx.x) * 4;
    int c = (int)((idx >> 10) & (C_ - 1));
    int isf32 = g_isf32;
    float mean = g_stats[c] * (1.0f / NPC_);
    float var  = g_stats[256 + c] * (1.0f / NPC_) - mean * mean;
    float rstd = rsqrtf(fmaxf(var, 0.f) + 1e-5f);
    float gv = ldq(g, c, isf32), bv = ldq(bb, c, isf32);
    float4 r = *(const float4*)(g_dw + idx);
    float4 h;
    h.x = fmaxf(0.f, (r.x - mean) * rstd * gv + bv);
    h.y = fmaxf(0.f, (r.y - mean) * rstd * gv + bv);
    h.z = fmaxf(0.f, (r.z - mean) * rstd * gv + bv);
    h.w = fmaxf(0.f, (r.w - mean) * rstd * gv + bv);
    *(float4*)(g_h + idx) = h;
}

// ---------------------------------------------------------------------------
// fused max+avg 3x3 pooling on g_h: max -> g_pm (slot 1), avg -> g_pa (slot 2)
// ---------------------------------------------------------------------------
__global__ __launch_bounds__(256)
void k_pool_fused() {
    const float s1 = g_sel[1], s2 = g_sel[2];
    if (s1 == 0.f && s2 == 0.f) return;
    __shared__ float xs[34 * 33];
    __shared__ float red[512];
    const int t = threadIdx.x;
    const int c = blockIdx.x & (C_ - 1);
    const int y  = t >> 3;
    const int x0 = (t & 7) * 4;
    const float* hp = g_h + (size_t)blockIdx.x * HW_;
    float4 r = *(const float4*)(hp + t * 4);
    float* xw = xs + y * 33 + x0;
    xw[0] = r.x; xw[1] = r.y; xw[2] = r.z; xw[3] = r.w;
    __syncthreads();
    float mx[4] = {0.f, 0.f, 0.f, 0.f};       // h >= 0 post-ReLU; matches padded max
    float sm[4] = {0.f, 0.f, 0.f, 0.f};
    #pragma unroll
    for (int ky = 0; ky < 3; ++ky) {
        int iy = y + ky - 1;
        if (iy < 0 || iy >= 32) continue;
        float row[6];
        #pragma unroll
        for (int i = 0; i < 6; ++i) {
            int ix = x0 + i - 1;
            row[i] = (ix >= 0 && ix < 32) ? xs[iy * 33 + ix] : 0.0f;
        }
        #pragma unroll
        for (int kx = 0; kx < 3; ++kx)
            #pragma unroll
            for (int j = 0; j < 4; ++j) {
                mx[j] = fmaxf(mx[j], row[j + kx]);
                sm[j] += row[j + kx];
            }
    }
    #pragma unroll
    for (int j = 0; j < 4; ++j) sm[j] *= (1.0f / 9.0f);
    const size_t ob = (size_t)blockIdx.x * HW_ + y * 32 + x0;
    if (s1 != 0.f) {
        float* o = g_pm + ob;
        o[0] = mx[0]; o[1] = mx[1]; o[2] = mx[2]; o[3] = mx[3];
        stats_epilogue(red, mx[0]+mx[1]+mx[2]+mx[3],
                       mx[0]*mx[0]+mx[1]*mx[1]+mx[2]*mx[2]+mx[3]*mx[3], t, c, 1);
    }
    if (s2 != 0.f) {
        float* o = g_pa + ob;
        o[0] = sm[0]; o[1] = sm[1]; o[2] = sm[2]; o[3] = sm[3];
        stats_epilogue(red, sm[0]+sm[1]+sm[2]+sm[3],
                       sm[0]*sm[0]+sm[1]*sm[1]+sm[2]*sm[2]+sm[3]*sm[3], t, c, 2);
    }
}

// ---------------------------------------------------------------------------
// FUSED dense convs v3: COUT=4, dbuf 1-barrier, ZERO-PADDED LDS (36 x 40,
// interior at +2,+2 -> no masks, rows via 2x ds_read_b128), float4 f32 weights
// (one dwordx4 per (ci,tap) covers all 4 output channels).
// grid = 64 b * 64 cg = 4096. Per ci per wave: 688 FMA, 43 w-loads, 10 LDS rows.
// ---------------------------------------------------------------------------
__global__ __launch_bounds__(256)
void k_conv_fused() {
    const bool h3 = (g_sel[4] != 0.f), h5 = (g_sel[5] != 0.f), hd = (g_sel[7] != 0.f);
    if (!h3 && !h5 && !hd) return;
    __shared__ float xs[2][36 * 40];
    __shared__ float red[1024];
    const int t  = threadIdx.x;
    const int cg = blockIdx.x & 63;
    const int c0 = cg * 4;
    const int b  = blockIdx.x >> 6;
    const int y  = t >> 3;
    const int x0 = (t & 7) * 4;
    const float* hb  = g_h + (size_t)b * C_ * HW_;
    const float* w5b = g_w5f + (size_t)cg * 25600;
    const float* w3b = g_w3f + (size_t)cg * 9216;
    const float* wdb = g_wdf + (size_t)cg * 9216;

    float a3[4][4], a5[4][4], ad[4][4];
    #pragma unroll
    for (int u = 0; u < 4; ++u)
        #pragma unroll
        for (int j = 0; j < 4; ++j) { a3[u][j] = 0.f; a5[u][j] = 0.f; ad[u][j] = 0.f; }

    // zero both padded tiles (borders stay zero forever -> free zero-padding)
    {
        float* xf = &xs[0][0];
        for (int i = t; i < 2 * 36 * 40; i += 256) xf[i] = 0.f;
    }
    __syncthreads();
    // prologue: stage ci=0 interior
    {
        float4 r0 = *(const float4*)(hb + t * 4);
        float* xw = xs[0] + (y + 2) * 40 + 2 + x0;
        xw[0] = r0.x; xw[1] = r0.y; xw[2] = r0.z; xw[3] = r0.w;
    }
    __syncthreads();
    int cur = 0;

    for (int ci = 0; ci < C_; ++ci) {
        // issue next-channel load EARLY (latency hides under the FMA body)
        float4 rN = {0.f, 0.f, 0.f, 0.f};
        if (ci + 1 < C_)
            rN = *(const float4*)(hb + (size_t)(ci + 1) * HW_ + t * 4);
        const float* xsc = xs[cur];
        const float* w5c = w5b + ci * 100;
        const float* w3c = w3b + ci * 36;
        const float* wdc = wdb + ci * 36;
        #pragma unroll
        for (int io = 0; io < 5; ++io) {
            // padded row read: 8 contiguous floats, 16B-aligned, no masks
            float4 ra = *(const float4*)(xsc + (y + io) * 40 + x0);
            float4 rb = *(const float4*)(xsc + (y + io) * 40 + x0 + 4);
            float row[8] = {ra.x, ra.y, ra.z, ra.w, rb.x, rb.y, rb.z, rb.w};
            if (h5) {
                #pragma unroll
                for (int kx = 0; kx < 5; ++kx) {
                    float4 w = *(const float4*)(w5c + (io * 5 + kx) * 4);
                    #pragma unroll
                    for (int j = 0; j < 4; ++j) {
                        a5[0][j] += row[j + kx] * w.x;
                        a5[1][j] += row[j + kx] * w.y;
                        a5[2][j] += row[j + kx] * w.z;
                        a5[3][j] += row[j + kx] * w.w;
                    }
                }
            }
            if (h3 && io >= 1 && io <= 3) {
                const int ky = io - 1;
                #pragma unroll
                for (int kx = 0; kx < 3; ++kx) {
                    float4 w = *(const float4*)(w3c + (ky * 3 + kx) * 4);
                    #pragma unroll
                    for (int j = 0; j < 4; ++j) {
                        a3[0][j] += row[j + kx + 1] * w.x;
                        a3[1][j] += row[j + kx + 1] * w.y;
                        a3[2][j] += row[j + kx + 1] * w.z;
                        a3[3][j] += row[j + kx + 1] * w.w;
                    }
                }
            }
            if (hd && (io & 1) == 0) {
                const int ky = io >> 1;
                #pragma unroll
                for (int kx = 0; kx < 3; ++kx) {
                    float4 w = *(const float4*)(wdc + (ky * 3 + kx) * 4);
                    #pragma unroll
                    for (int j = 0; j < 4; ++j) {
                        ad[0][j] += row[j + 2 * kx] * w.x;
                        ad[1][j] += row[j + 2 * kx] * w.y;
                        ad[2][j] += row[j + 2 * kx] * w.z;
                        ad[3][j] += row[j + 2 * kx] * w.w;
                    }
                }
            }
        }
        // write-late into the other buffer; single barrier per ci (proven R2)
        if (ci + 1 < C_) {
            float* xw = xs[cur ^ 1] + (y + 2) * 40 + 2 + x0;
            xw[0] = rN.x; xw[1] = rN.y; xw[2] = rN.z; xw[3] = rN.w;
        }
        __syncthreads();
        cur ^= 1;
    }

    size_t ob[4];
    #pragma unroll
    for (int u = 0; u < 4; ++u)
        ob[u] = (size_t)(b * C_ + c0 + u) * HW_ + y * 32 + x0;

    if (h3) {
        #pragma unroll
        for (int u = 0; u < 4; ++u) {
            float4 o; o.x = a3[u][0]; o.y = a3[u][1]; o.z = a3[u][2]; o.w = a3[u][3];
            *(float4*)(g_c3 + ob[u]) = o;
        }
        #pragma unroll
        for (int u = 0; u < 4; u += 2)
            stats_ep2(red, t,
                a3[u][0]+a3[u][1]+a3[u][2]+a3[u][3],
                a3[u][0]*a3[u][0]+a3[u][1]*a3[u][1]+a3[u][2]*a3[u][2]+a3[u][3]*a3[u][3],
                a3[u+1][0]+a3[u+1][1]+a3[u+1][2]+a3[u+1][3],
                a3[u+1][0]*a3[u+1][0]+a3[u+1][1]*a3[u+1][1]+a3[u+1][2]*a3[u+1][2]+a3[u+1][3]*a3[u+1][3],
                c0 + u, c0 + u + 1, 4);
    }
    if (h5) {
        #pragma unroll
        for (int u = 0; u < 4; ++u) {
            float4 o; o.x = a5[u][0]; o.y = a5[u][1]; o.z = a5[u][2]; o.w = a5[u][3];
            *(float4*)(g_c5 + ob[u]) = o;
        }
        #pragma unroll
        for (int u = 0; u < 4; u += 2)
            stats_ep2(red, t,
                a5[u][0]+a5[u][1]+a5[u][2]+a5[u][3],
                a5[u][0]*a5[u][0]+a5[u][1]*a5[u][1]+a5[u][2]*a5[u][2]+a5[u][3]*a5[u][3],
                a5[u+1][0]+a5[u+1][1]+a5[u+1][2]+a5[u+1][3],
                a5[u+1][0]*a5[u+1][0]+a5[u+1][1]*a5[u+1][1]+a5[u+1][2]*a5[u+1][2]+a5[u+1][3]*a5[u+1][3],
                c0 + u, c0 + u + 1, 5);
    }
    if (hd) {
        #pragma unroll
        for (int u = 0; u < 4; ++u) {
            float4 o; o.x = ad[u][0]; o.y = ad[u][1]; o.z = ad[u][2]; o.w = ad[u][3];
            *(float4*)(g_cd + ob[u]) = o;
        }
        #pragma unroll
        for (int u = 0; u < 4; u += 2)
            stats_ep2(red, t,
                ad[u][0]+ad[u][1]+ad[u][2]+ad[u][3],
                ad[u][0]*ad[u][0]+ad[u][1]*ad[u][1]+ad[u][2]*ad[u][2]+ad[u][3]*ad[u][3],
                ad[u+1][0]+ad[u+1][1]+ad[u+1][2]+ad[u+1][3],
                ad[u+1][0]*ad[u+1][0]+ad[u+1][1]*ad[u+1][1]+ad[u+1][2]*ad[u+1][2]+ad[u+1][3]*ad[u+1][3],
                c0 + u, c0 + u + 1, 7);
    }
}

// ---------------------------------------------------------------------------
// depthwise 3x3: g_h -> g_dw (g_h preserved for the skip term in k_final_all)
// ---------------------------------------------------------------------------
__global__ __launch_bounds__(256)
void k_dw(const void* __restrict__ wt) {
    if (g_sel[6] == 0.0f) return;
    __shared__ float xs[34 * 33];
    const int t = threadIdx.x;
    const int c = blockIdx.x & (C_ - 1);
    const int y  = t >> 3;
    const int x0 = (t & 7) * 4;
    const int isf32 = g_isf32;
    const float* hp = g_h + (size_t)blockIdx.x * HW_;
    float4 r = *(const float4*)(hp + t * 4);
    float* xw = xs + y * 33 + x0;
    xw[0] = r.x; xw[1] = r.y; xw[2] = r.z; xw[3] = r.w;
    __syncthreads();
    float wv[9];
    #pragma unroll
    for (int k = 0; k < 9; ++k) wv[k] = ldq(wt, (long)c * 9 + k, isf32);
    float acc[4] = {0.f, 0.f, 0.f, 0.f};
    #pragma unroll
    for (int ky = 0; ky < 3; ++ky) {
        int iy = y + ky - 1;
        if (iy < 0 || iy >= 32) continue;
        float row[6];
        #pragma unroll
        for (int i = 0; i < 6; ++i) {
            int ix = x0 + i - 1;
            row[i] = (ix >= 0 && ix < 32) ? xs[iy * 33 + ix] : 0.0f;
        }
        #pragma unroll
        for (int kx = 0; kx < 3; ++kx)
            #pragma unroll
            for (int j = 0; j < 4; ++j)
                acc[j] += row[j + kx] * wv[ky * 3 + kx];
    }
    float* o = g_dw + (size_t)blockIdx.x * HW_ + y * 32 + x0;
    o[0] = acc[0]; o[1] = acc[1]; o[2] = acc[2]; o[3] = acc[3];
}

// ---------------------------------------------------------------------------
// pointwise 1x1 conv on g_dw, COUT=8 -> g_pw + fused stats slot 6
// ---------------------------------------------------------------------------
__global__ __launch_bounds__(256)
void k_pw(const void* __restrict__ wt) {
    if (g_sel[6] == 0.0f) return;
    __shared__ float xs[HW_];
    __shared__ float red[1024];
    const int t = threadIdx.x;
    const int c0 = (blockIdx.x & 31) * 8;
    const int b  = blockIdx.x >> 5;
    const int isf32 = g_isf32;
    const float* hb = g_dw + (size_t)b * C_ * HW_;
    float acc[8][4];
    #pragma unroll
    for (int k = 0; k < 8; ++k)
        #pragma unroll
        for (int j = 0; j < 4; ++j) acc[k][j] = 0.f;
    for (int ci = 0; ci < C_; ++ci) {
        __syncthreads();
        float4 r = *(const float4*)(hb + (size_t)ci * HW_ + t * 4);
        xs[t*4+0] = r.x; xs[t*4+1] = r.y; xs[t*4+2] = r.z; xs[t*4+3] = r.w;
        __syncthreads();
        const float x0v = xs[t], x1v = xs[t + 256], x2v = xs[t + 512], x3v = xs[t + 768];
        #pragma unroll
        for (int k = 0; k < 8; ++k) {
            float wv = ldq(wt, (long)(c0 + k) * C_ + ci, isf32);
            acc[k][0] += x0v * wv; acc[k][1] += x1v * wv;
            acc[k][2] += x2v * wv; acc[k][3] += x3v * wv;
        }
    }
    #pragma unroll
    for (int k = 0; k < 8; ++k) {
        float* o = g_pw + (size_t)(b * C_ + c0 + k) * HW_;
        o[t] = acc[k][0]; o[t + 256] = acc[k][1];
        o[t + 512] = acc[k][2]; o[t + 768] = acc[k][3];
    }
    #pragma unroll
    for (int k = 0; k < 8; k += 2) {
        float sA  = acc[k][0] + acc[k][1] + acc[k][2] + acc[k][3];
        float s2A = acc[k][0]*acc[k][0] + acc[k][1]*acc[k][1]
                  + acc[k][2]*acc[k][2] + acc[k][3]*acc[k][3];
        float sB  = acc[k+1][0] + acc[k+1][1] + acc[k+1][2] + acc[k+1][3];
        float s2B = acc[k+1][0]*acc[k+1][0] + acc[k+1][1]*acc[k+1][1]
                  + acc[k+1][2]*acc[k+1][2] + acc[k+1][3]*acc[k+1][3];
        stats_ep2(red, t, sA, s2A, sB, s2B, c0 + k, c0 + k + 1, 6);
    }
}

// ---------------------------------------------------------------------------
// single fused epilogue: out = sel3*h + Σ sel_k * BN_k(buf_k), dtype-dual
// ---------------------------------------------------------------------------
__device__ __forceinline__ void bn_term(float4& o, const float* buf, size_t idx,
                                        int c, int slot, float sv,
                                        const void* g, const void* bb, int isf32) {
    float mean = g_stats[slot * 512 + c] * (1.0f / NPC_);
    float var  = g_stats[slot * 512 + 256 + c] * (1.0f / NPC_) - mean * mean;
    float rstd = rsqrtf(fmaxf(var, 0.f) + 1e-5f);
    float gv = ldq(g, c, isf32), bv = ldq(bb, c, isf32);
    float4 r = *(const float4*)(buf + idx);
    o.x += sv * ((r.x - mean) * rstd * gv + bv);
    o.y += sv * ((r.y - mean) * rstd * gv + bv);
    o.z += sv * ((r.z - mean) * rstd * gv + bv);
    o.w += sv * ((r.w - mean) * rstd * gv + bv);
}

__global__ __launch_bounds__(256)
void k_final_all(void* __restrict__ out,
                 const void* __restrict__ gmp, const void* __restrict__ bmp,
                 const void* __restrict__ gap, const void* __restrict__ bap,
                 const void* __restrict__ g3,  const void* __restrict__ b3,
                 const void* __restrict__ g5,  const void* __restrict__ b5,
                 const void* __restrict__ gs,  const void* __restrict__ bs,
                 const void* __restrict__ gd,  const void* __restrict__ bd) {
    size_t idx = ((size_t)blockIdx.x * 256 + threadIdx.x) * 4;
    int c = (int)((idx >> 10) & (C_ - 1));
    int isf32 = g_isf32;
    float4 o = {0.f, 0.f, 0.f, 0.f};
    float s3 = g_sel[3];
    if (s3 != 0.f) {
        float4 h = *(const float4*)(g_h + idx);
        o.x = s3 * h.x; o.y = s3 * h.y; o.z = s3 * h.z; o.w = s3 * h.w;
    }
    float sv;
    if ((sv = g_sel[1]) != 0.f) bn_term(o, g_pm, idx, c, 1, sv, gmp, bmp, isf32);
    if ((sv = g_sel[2]) != 0.f) bn_term(o, g_pa, idx, c, 2, sv, gap, bap, isf32);
    if ((sv = g_sel[4]) != 0.f) bn_term(o, g_c3, idx, c, 4, sv, g3,  b3,  isf32);
    if ((sv = g_sel[5]) != 0.f) bn_term(o, g_c5, idx, c, 5, sv, g5,  b5,  isf32);
    if ((sv = g_sel[6]) != 0.f) bn_term(o, g_pw, idx, c, 6, sv, gs,  bs,  isf32);
    if ((sv = g_sel[7]) != 0.f) bn_term(o, g_cd, idx, c, 7, sv, gd,  bd,  isf32);
    if (isf32) {
        *(float4*)((float*)out + idx) = o;
    } else {
        ushort4 u; u.x = f2u(o.x); u.y = f2u(o.y); u.z = f2u(o.z); u.w = f2u(o.w);
        *(ushort4*)((unsigned short*)out + idx) = u;
    }
}

// ---------------------------------------------------------------------------
extern "C" void kernel_launch(void* const* d_in, const int* in_sizes, int n_in,
                              void* d_out, int out_size, void* d_ws, size_t ws_size,
                              hipStream_t stream) {
    const void* x    = d_in[0];
    const void* aw   = d_in[1];
    const void* w_in = d_in[2];
    const void* g_in = d_in[3];
    const void* b_in = d_in[4];
    const void* w3   = d_in[5];
    const void* g3   = d_in[6];
    const void* b3   = d_in[7];
    const void* w5   = d_in[8];
    const void* g5   = d_in[9];
    const void* b5   = d_in[10];
    const void* wdw  = d_in[11];
    const void* wpw  = d_in[12];
    const void* gs   = d_in[13];
    const void* bs   = d_in[14];
    const void* wd   = d_in[15];
    const void* gd   = d_in[16];
    const void* bd   = d_in[17];
    const void* gmp  = d_in[18];
    const void* bmp  = d_in[19];
    const void* gap  = d_in[20];
    const void* bap  = d_in[21];

    dim3 Bk(256);
    dim3 Gfull(NB_);    // 16384 elementwise / per-(b,c) blocks
    dim3 Gc8(2048);     // COUT=8 1x1-conv blocks
    dim3 Gcv(4096);     // COUT=4 fused dense-conv blocks

    k_prep<<<dim3(1), Bk, 0, stream>>>(x, aw);
    k_wconv<<<dim3(64), Bk, 0, stream>>>(w3, w5, wd, w_in);

    // transition: 1x1 conv (COUT=8, f32 packed weights, dbuf) -> g_dw; BN+ReLU
    k_trans<<<Gc8, Bk, 0, stream>>>(x);
    k_bnrelu<<<Gfull, Bk, 0, stream>>>(g_in, b_in);

    // ops 1+2: fused max/avg pool -> g_pm/g_pa
    k_pool_fused<<<Gfull, Bk, 0, stream>>>();

    // ops 4+5+7: fused dense convs v3 -> g_c3/g_c5/g_cd
    k_conv_fused<<<Gcv, Bk, 0, stream>>>();

    // op 6: sep_conv_3x3: dw (g_h -> g_dw), pw (g_dw -> g_pw)
    k_dw<<<Gfull, Bk, 0, stream>>>(wdw);
    k_pw<<<Gc8, Bk, 0, stream>>>(wpw);

    // single fused epilogue: out = sel3*h + sum sel_k*BN_k(buf_k)
    k_final_all<<<Gfull, Bk, 0, stream>>>(d_out,
        gmp, bmp, gap, bap, g3, b3, g5, b5, gs, bs, gd, bd);
}

// Round 5
// 1219.433 us; speedup vs baseline: 3.0696x; 1.4321x over previous
//
#include <hip/hip_runtime.h>

#define CIN_  128
#define C_    256
#define HW_   1024      /* 32*32 */
#define NPC_  65536.0f  /* 64*1024 elements per channel for BN stats */
#define NB_   16384     /* 64 batches * 256 channels */

constexpr size_t NELEM = 16777216ull;   // 64*256*32*32

// ---- module-scope device scratch: one buffer per producer (no reuse hazards)
__device__ float g_sel[8];
__device__ float g_stats[8 * 512];      // per-slot: [0..255]=sum, [256..511]=sumsq
__device__ int   g_isf32;
__device__ float g_h[NELEM];            // relu(BN0(trans))
__device__ float g_c3[NELEM];           // conv3x3 out      (slot 4)
__device__ float g_c5[NELEM];           // conv5x5 out      (slot 5)
__device__ float g_cd[NELEM];           // dil conv out     (slot 7)
__device__ float g_pm[NELEM];           // maxpool out      (slot 1)
__device__ float g_pa[NELEM];           // avgpool out      (slot 2)
__device__ float g_pw[NELEM];           // pointwise out    (slot 6)
__device__ float g_dw[NELEM];           // trans tmp, then depthwise out

// ---- prepass-converted f32 weights, packed co-fastest (8 per tap) ----------
// g_w5f: [cg=32][ci=256][tap=25][u=8]  (co = cg*8+u)
// g_w3f/g_wdf: [cg=32][ci=256][tap=9][u=8]
// g_wtf: [cg=32][ci=128][u=8]          (transition conv)
__device__ float g_w5f[32 * 256 * 25 * 8];
__device__ float g_w3f[32 * 256 * 9 * 8];
__device__ float g_wdf[32 * 256 * 9 * 8];
__device__ float g_wtf[32 * 128 * 8];

__device__ __forceinline__ float u2f(unsigned short u) {
    union { unsigned int i; float f; } x; x.i = ((unsigned int)u) << 16; return x.f;
}
__device__ __forceinline__ unsigned short f2u(float f) {
    union { float f; unsigned int i; } x; x.f = f;
    unsigned int r = x.i + 0x7fffu + ((x.i >> 16) & 1u);  // RNE
    return (unsigned short)(r >> 16);
}
__device__ __forceinline__ float ldq(const void* p, long i, int isf32) {
    return isf32 ? ((const float*)p)[i] : u2f(((const unsigned short*)p)[i]);
}

// ---------------------------------------------------------------------------
// prep: zero stats, detect input dtype, compute sel
// ---------------------------------------------------------------------------
__global__ void k_prep(const void* __restrict__ x, const void* __restrict__ aw) {
    __shared__ int flag_s;
    __shared__ float red[256];
    const int t = threadIdx.x;
    for (int i = t; i < 8 * 512; i += 256) g_stats[i] = 0.f;
    const unsigned short* xu = (const unsigned short*)x;
    int bad = 0;
    for (int i = t; i < 8192; i += 256) {
        unsigned int e = (xu[i] >> 7) & 0xFFu;
        if (e >= 0xC6u) ++bad;
    }
    red[t] = (float)bad;
    __syncthreads();
    for (int off = 128; off > 0; off >>= 1) {
        if (t < off) red[t] += red[t + off];
        __syncthreads();
    }
    if (t == 0) { flag_s = (red[0] > 4.0f) ? 1 : 0; g_isf32 = flag_s; }
    __syncthreads();
    const int isf32 = flag_s;
    if (t == 0) {
        float w[8];
        float mx = -1e30f;
        for (int i = 0; i < 8; ++i) { w[i] = ldq(aw, i, isf32); mx = fmaxf(mx, w[i]); }
        float s = 0.f;
        for (int i = 0; i < 8; ++i) { w[i] = expf(w[i] - mx); s += w[i]; }
        for (int i = 0; i < 8; ++i) w[i] /= s;
        float sv[8] = {0,0,0,0,0,0,0,0};
        bool used[8] = {false,false,false,false,false,false,false,false};
        for (int k = 0; k < 3; ++k) {          // top-3, first-index tie-break
            int bi = -1; float bv = -1.f;
            for (int i = 0; i < 8; ++i) if (!used[i] && w[i] > bv) { bv = w[i]; bi = i; }
            used[bi] = true; sv[bi] = bv;
        }
        float tot = 0.f;
        for (int i = 0; i < 8; ++i) { if (sv[i] < 0.01f) sv[i] = 0.f; tot += sv[i]; }
        tot = fmaxf(tot, 1e-12f);
        for (int i = 0; i < 8; ++i) g_sel[i] = sv[i] / tot;
    }
}

// ---------------------------------------------------------------------------
// weight prepass: convert to f32, repack co-fastest (2x float4 per (ci,tap)).
// grid = 32 blocks (cg). Runs after k_prep (needs g_isf32).
// ---------------------------------------------------------------------------
__global__ __launch_bounds__(256)
void k_wconv(const void* __restrict__ w3, const void* __restrict__ w5,
             const void* __restrict__ wd, const void* __restrict__ wi) {
    const int cg = blockIdx.x;          // 0..31
    const int t  = threadIdx.x;
    const int isf32 = g_isf32;
    // w5: out o = ((ci*25+tap)*8+u)
    for (int o = t; o < 51200; o += 256) {
        int u = o & 7, r = o >> 3, tap = r % 25, ci = r / 25;
        g_w5f[(size_t)cg * 51200 + o] =
            ldq(w5, ((long)(cg * 8 + u) * C_ + ci) * 25 + tap, isf32);
    }
    // w3 / wd: out o = ((ci*9+tap)*8+u)
    for (int o = t; o < 18432; o += 256) {
        int u = o & 7, r = o >> 3, tap = r % 9, ci = r / 9;
        long ii = ((long)(cg * 8 + u) * C_ + ci) * 9 + tap;
        g_w3f[(size_t)cg * 18432 + o] = ldq(w3, ii, isf32);
        g_wdf[(size_t)cg * 18432 + o] = ldq(wd, ii, isf32);
    }
    // transition weights: [cg=32][ci=128][u=8]
    for (int o = t; o < 1024; o += 256) {
        int u = o & 7, ci = o >> 3;
        g_wtf[cg * 1024 + o] = ldq(wi, (long)(cg * 8 + u) * CIN_ + ci, isf32);
    }
}

// ---------------------------------------------------------------------------
// stats epilogues: single-channel (red[512]) and channel-pair (red[1024])
// ---------------------------------------------------------------------------
__device__ __forceinline__ void stats_epilogue(float* red, float s, float s2,
                                               int t, int c, int slot) {
    __syncthreads();
    red[t] = s; red[t + 256] = s2;
    __syncthreads();
    for (int off = 128; off > 0; off >>= 1) {
        if (t < off) { red[t] += red[t + off]; red[t + 256] += red[t + 256 + off]; }
        __syncthreads();
    }
    if (t == 0) {
        atomicAdd(&g_stats[slot * 512 + c], red[0]);
        atomicAdd(&g_stats[slot * 512 + 256 + c], red[256]);
    }
}

__device__ __forceinline__ void stats_ep2(float* red, int t,
                                          float sA, float s2A, float sB, float s2B,
                                          int cA, int cB, int slot) {
    __syncthreads();
    red[t] = sA; red[t + 256] = s2A; red[t + 512] = sB; red[t + 768] = s2B;
    __syncthreads();
    for (int off = 128; off > 0; off >>= 1) {
        if (t < off) {
            red[t]       += red[t + off];
            red[t + 256] += red[t + 256 + off];
            red[t + 512] += red[t + 512 + off];
            red[t + 768] += red[t + 768 + off];
        }
        __syncthreads();
    }
    if (t == 0) {
        atomicAdd(&g_stats[slot * 512 + cA],       red[0]);
        atomicAdd(&g_stats[slot * 512 + 256 + cA], red[256]);
        atomicAdd(&g_stats[slot * 512 + cB],       red[512]);
        atomicAdd(&g_stats[slot * 512 + 256 + cB], red[768]);
    }
}

// ---------------------------------------------------------------------------
// transition 1x1 conv, COUT=8, f32 float4 weights, dbuf 1-barrier pipeline
// -> g_dw, stats slot 0. grid = 64 b * 32 cgroups = 2048
// ---------------------------------------------------------------------------
__global__ __launch_bounds__(256)
void k_trans(const void* __restrict__ xin) {
    __shared__ float xs[2][HW_];
    __shared__ float red[1024];
    const int t  = threadIdx.x;
    const int cg = blockIdx.x & 31;
    const int c0 = cg * 8;
    const int b  = blockIdx.x >> 5;
    const int isf32 = g_isf32;
    const float* wb = g_wtf + cg * 1024;
    float acc[8][4];
    #pragma unroll
    for (int k = 0; k < 8; ++k)
        #pragma unroll
        for (int j = 0; j < 4; ++j) acc[k][j] = 0.f;

    // prologue: stage ci=0
    {
        size_t vi = (size_t)(b * CIN_) * 256 + t;
        float4 r0;
        if (isf32) r0 = ((const float4*)xin)[vi];
        else {
            ushort4 r = ((const ushort4*)xin)[vi];
            r0.x = u2f(r.x); r0.y = u2f(r.y); r0.z = u2f(r.z); r0.w = u2f(r.w);
        }
        xs[0][t*4+0] = r0.x; xs[0][t*4+1] = r0.y;
        xs[0][t*4+2] = r0.z; xs[0][t*4+3] = r0.w;
    }
    __syncthreads();
    int cur = 0;
    for (int ci = 0; ci < CIN_; ++ci) {
        float4 rN = {0.f, 0.f, 0.f, 0.f};
        if (ci + 1 < CIN_) {
            size_t vi = (size_t)(b * CIN_ + ci + 1) * 256 + t;
            if (isf32) rN = ((const float4*)xin)[vi];
            else {
                ushort4 r = ((const ushort4*)xin)[vi];
                rN.x = u2f(r.x); rN.y = u2f(r.y); rN.z = u2f(r.z); rN.w = u2f(r.w);
            }
        }
        const float x0v = xs[cur][t      ], x1v = xs[cur][t + 256];
        const float x2v = xs[cur][t + 512], x3v = xs[cur][t + 768];
        float4 wq0 = *(const float4*)(wb + ci * 8);
        float4 wq1 = *(const float4*)(wb + ci * 8 + 4);
        acc[0][0] += x0v*wq0.x; acc[0][1] += x1v*wq0.x; acc[0][2] += x2v*wq0.x; acc[0][3] += x3v*wq0.x;
        acc[1][0] += x0v*wq0.y; acc[1][1] += x1v*wq0.y; acc[1][2] += x2v*wq0.y; acc[1][3] += x3v*wq0.y;
        acc[2][0] += x0v*wq0.z; acc[2][1] += x1v*wq0.z; acc[2][2] += x2v*wq0.z; acc[2][3] += x3v*wq0.z;
        acc[3][0] += x0v*wq0.w; acc[3][1] += x1v*wq0.w; acc[3][2] += x2v*wq0.w; acc[3][3] += x3v*wq0.w;
        acc[4][0] += x0v*wq1.x; acc[4][1] += x1v*wq1.x; acc[4][2] += x2v*wq1.x; acc[4][3] += x3v*wq1.x;
        acc[5][0] += x0v*wq1.y; acc[5][1] += x1v*wq1.y; acc[5][2] += x2v*wq1.y; acc[5][3] += x3v*wq1.y;
        acc[6][0] += x0v*wq1.z; acc[6][1] += x1v*wq1.z; acc[6][2] += x2v*wq1.z; acc[6][3] += x3v*wq1.z;
        acc[7][0] += x0v*wq1.w; acc[7][1] += x1v*wq1.w; acc[7][2] += x2v*wq1.w; acc[7][3] += x3v*wq1.w;
        if (ci + 1 < CIN_) {
            float* xw = xs[cur ^ 1] + t * 4;
            xw[0] = rN.x; xw[1] = rN.y; xw[2] = rN.z; xw[3] = rN.w;
        }
        __syncthreads();
        cur ^= 1;
    }
    #pragma unroll
    for (int k = 0; k < 8; ++k) {
        float* o = g_dw + (size_t)(b * C_ + c0 + k) * HW_;
        o[t] = acc[k][0]; o[t + 256] = acc[k][1];
        o[t + 512] = acc[k][2]; o[t + 768] = acc[k][3];
    }
    #pragma unroll
    for (int k = 0; k < 8; k += 2) {
        float sA  = acc[k][0] + acc[k][1] + acc[k][2] + acc[k][3];
        float s2A = acc[k][0]*acc[k][0] + acc[k][1]*acc[k][1]
                  + acc[k][2]*acc[k][2] + acc[k][3]*acc[k][3];
        float sB  = acc[k+1][0] + acc[k+1][1] + acc[k+1][2] + acc[k+1][3];
        float s2B = acc[k+1][0]*acc[k+1][0] + acc[k+1][1]*acc[k+1][1]
                  + acc[k+1][2]*acc[k+1][2] + acc[k+1][3]*acc[k+1][3];
        stats_ep2(red, t, sA, s2A, sB, s2B, c0 + k, c0 + k + 1, 0);
    }
}

// ---------------------------------------------------------------------------
// g_h = relu(BN0(g_dw))
// ---------------------------------------------------------------------------
__global__ __launch_bounds__(256)
void k_bnrelu(const void* __restrict__ g, const void* __restrict__ bb) {
    size_t idx = ((size_t)blockIdx.x * 256 + threadIdx.x) * 4;
    int c = (int)((idx >> 10) & (C_ - 1));
    int isf32 = g_isf32;
    float mean = g_stats[c] * (1.0f / NPC_);
    float var  = g_stats[256 + c] * (1.0f / NPC_) - mean * mean;
    float rstd = rsqrtf(fmaxf(var, 0.f) + 1e-5f);
    float gv = ldq(g, c, isf32), bv = ldq(bb, c, isf32);
    float4 r = *(const float4*)(g_dw + idx);
    float4 h;
    h.x = fmaxf(0.f, (r.x - mean) * rstd * gv + bv);
    h.y = fmaxf(0.f, (r.y - mean) * rstd * gv + bv);
    h.z = fmaxf(0.f, (r.z - mean) * rstd * gv + bv);
    h.w = fmaxf(0.f, (r.w - mean) * rstd * gv + bv);
    *(float4*)(g_h + idx) = h;
}

// ---------------------------------------------------------------------------
// fused max+avg 3x3 pooling on g_h: max -> g_pm (slot 1), avg -> g_pa (slot 2)
// ---------------------------------------------------------------------------
__global__ __launch_bounds__(256)
void k_pool_fused() {
    const float s1 = g_sel[1], s2 = g_sel[2];
    if (s1 == 0.f && s2 == 0.f) return;
    __shared__ float xs[34 * 33];
    __shared__ float red[512];
    const int t = threadIdx.x;
    const int c = blockIdx.x & (C_ - 1);
    const int y  = t >> 3;
    const int x0 = (t & 7) * 4;
    const float* hp = g_h + (size_t)blockIdx.x * HW_;
    float4 r = *(const float4*)(hp + t * 4);
    float* xw = xs + y * 33 + x0;
    xw[0] = r.x; xw[1] = r.y; xw[2] = r.z; xw[3] = r.w;
    __syncthreads();
    float mx[4] = {0.f, 0.f, 0.f, 0.f};       // h >= 0 post-ReLU; matches padded max
    float sm[4] = {0.f, 0.f, 0.f, 0.f};
    #pragma unroll
    for (int ky = 0; ky < 3; ++ky) {
        int iy = y + ky - 1;
        if (iy < 0 || iy >= 32) continue;
        float row[6];
        #pragma unroll
        for (int i = 0; i < 6; ++i) {
            int ix = x0 + i - 1;
            row[i] = (ix >= 0 && ix < 32) ? xs[iy * 33 + ix] : 0.0f;
        }
        #pragma unroll
        for (int kx = 0; kx < 3; ++kx)
            #pragma unroll
            for (int j = 0; j < 4; ++j) {
                mx[j] = fmaxf(mx[j], row[j + kx]);
                sm[j] += row[j + kx];
            }
    }
    #pragma unroll
    for (int j = 0; j < 4; ++j) sm[j] *= (1.0f / 9.0f);
    const size_t ob = (size_t)blockIdx.x * HW_ + y * 32 + x0;
    if (s1 != 0.f) {
        float* o = g_pm + ob;
        o[0] = mx[0]; o[1] = mx[1]; o[2] = mx[2]; o[3] = mx[3];
        stats_epilogue(red, mx[0]+mx[1]+mx[2]+mx[3],
                       mx[0]*mx[0]+mx[1]*mx[1]+mx[2]*mx[2]+mx[3]*mx[3], t, c, 1);
    }
    if (s2 != 0.f) {
        float* o = g_pa + ob;
        o[0] = sm[0]; o[1] = sm[1]; o[2] = sm[2]; o[3] = sm[3];
        stats_epilogue(red, sm[0]+sm[1]+sm[2]+sm[3],
                       sm[0]*sm[0]+sm[1]*sm[1]+sm[2]*sm[2]+sm[3]*sm[3], t, c, 2);
    }
}

// ---------------------------------------------------------------------------
// SPECIALIZED dense conv, COUT=8, dbuf 1-barrier, zero-padded LDS tile
// (rows 32+2*PAD x 40, interior at col 4 -> all staging/reads aligned).
// Only the needed KS rows are read per ci; window = minimal aligned loads.
// grid = 64 b * 32 cg = 2048. Early-exits if its op isn't selected.
// Per ci per thread (KS=3): 288 FMA, 18 w-loads, 9 LDS reads, 1 stage write.
// ---------------------------------------------------------------------------
template<int KS, int DIL, int PAD, int SLOT>
__global__ __launch_bounds__(256)
void k_conv1() {
    if (g_sel[SLOT] == 0.0f) return;
    constexpr int TR   = 32 + 2 * PAD;      // tile rows
    constexpr int TAPS = KS * KS;
    __shared__ float xs[2][TR * 40];
    __shared__ float red[1024];
    const int t  = threadIdx.x;
    const int cg = blockIdx.x & 31;
    const int c0 = cg * 8;
    const int b  = blockIdx.x >> 5;
    const int y  = t >> 3;
    const int x0 = (t & 7) * 4;
    const float* hb = g_h + (size_t)b * C_ * HW_;
    const float* wb = (SLOT == 4 ? g_w3f : SLOT == 5 ? g_w5f : g_wdf)
                      + (size_t)cg * (C_ * TAPS * 8);
    float* obuf = (SLOT == 4) ? g_c3 : (SLOT == 5) ? g_c5 : g_cd;

    float acc[8][4];
    #pragma unroll
    for (int u = 0; u < 8; ++u)
        #pragma unroll
        for (int j = 0; j < 4; ++j) acc[u][j] = 0.f;

    // zero both padded tiles (borders stay zero forever -> free zero-padding)
    {
        float* xf = &xs[0][0];
        for (int i = t; i < 2 * TR * 40; i += 256) xf[i] = 0.f;
    }
    __syncthreads();
    // prologue: stage ci=0 interior (16B-aligned single b128 write)
    {
        float4 r0 = *(const float4*)(hb + t * 4);
        *(float4*)(xs[0] + (y + PAD) * 40 + 4 + x0) = r0;
    }
    __syncthreads();
    int cur = 0;

    for (int ci = 0; ci < C_; ++ci) {
        // issue next-channel load EARLY (latency hides under the FMA body)
        float4 rN = {0.f, 0.f, 0.f, 0.f};
        if (ci + 1 < C_)
            rN = *(const float4*)(hb + (size_t)(ci + 1) * HW_ + t * 4);
        const float* xsc = xs[cur];
        const float* wc  = wb + ci * (TAPS * 8);
        #pragma unroll
        for (int ky = 0; ky < KS; ++ky) {
            const int rr = (y + ky * DIL) * 40 + x0;
            // minimal aligned window: padded cols x0+(4-PAD) .. x0+(4-PAD)+3+(KS-1)*DIL
            float wnd[12];
            if (PAD == 1) {                 // need cols x0+3..x0+8
                wnd[3] = xsc[rr + 3];
                float4 qb = *(const float4*)(xsc + rr + 4);
                wnd[4] = qb.x; wnd[5] = qb.y; wnd[6] = qb.z; wnd[7] = qb.w;
                wnd[8] = xsc[rr + 8];
            } else {                        // need cols x0+2..x0+9
                float2 qa = *(const float2*)(xsc + rr + 2);
                float4 qb = *(const float4*)(xsc + rr + 4);
                float2 qc = *(const float2*)(xsc + rr + 8);
                wnd[2] = qa.x; wnd[3] = qa.y;
                wnd[4] = qb.x; wnd[5] = qb.y; wnd[6] = qb.z; wnd[7] = qb.w;
                wnd[8] = qc.x; wnd[9] = qc.y;
            }
            #pragma unroll
            for (int kx = 0; kx < KS; ++kx) {
                const float4 wA = *(const float4*)(wc + (ky * KS + kx) * 8);
                const float4 wB = *(const float4*)(wc + (ky * KS + kx) * 8 + 4);
                #pragma unroll
                for (int j = 0; j < 4; ++j) {
                    const float v = wnd[(4 - PAD) + j + kx * DIL];
                    acc[0][j] += v * wA.x; acc[1][j] += v * wA.y;
                    acc[2][j] += v * wA.z; acc[3][j] += v * wA.w;
                    acc[4][j] += v * wB.x; acc[5][j] += v * wB.y;
                    acc[6][j] += v * wB.z; acc[7][j] += v * wB.w;
                }
            }
        }
        // write-late into the other buffer; single barrier per ci (proven R2)
        if (ci + 1 < C_)
            *(float4*)(xs[cur ^ 1] + (y + PAD) * 40 + 4 + x0) = rN;
        __syncthreads();
        cur ^= 1;
    }

    #pragma unroll
    for (int u = 0; u < 8; ++u) {
        float4 o; o.x = acc[u][0]; o.y = acc[u][1]; o.z = acc[u][2]; o.w = acc[u][3];
        *(float4*)(obuf + (size_t)(b * C_ + c0 + u) * HW_ + y * 32 + x0) = o;
    }
    #pragma unroll
    for (int u = 0; u < 8; u += 2)
        stats_ep2(red, t,
            acc[u][0]+acc[u][1]+acc[u][2]+acc[u][3],
            acc[u][0]*acc[u][0]+acc[u][1]*acc[u][1]+acc[u][2]*acc[u][2]+acc[u][3]*acc[u][3],
            acc[u+1][0]+acc[u+1][1]+acc[u+1][2]+acc[u+1][3],
            acc[u+1][0]*acc[u+1][0]+acc[u+1][1]*acc[u+1][1]+acc[u+1][2]*acc[u+1][2]+acc[u+1][3]*acc[u+1][3],
            c0 + u, c0 + u + 1, SLOT);
}

// ---------------------------------------------------------------------------
// depthwise 3x3: g_h -> g_dw (g_h preserved for the skip term in k_final_all)
// ---------------------------------------------------------------------------
__global__ __launch_bounds__(256)
void k_dw(const void* __restrict__ wt) {
    if (g_sel[6] == 0.0f) return;
    __shared__ float xs[34 * 33];
    const int t = threadIdx.x;
    const int c = blockIdx.x & (C_ - 1);
    const int y  = t >> 3;
    const int x0 = (t & 7) * 4;
    const int isf32 = g_isf32;
    const float* hp = g_h + (size_t)blockIdx.x * HW_;
    float4 r = *(const float4*)(hp + t * 4);
    float* xw = xs + y * 33 + x0;
    xw[0] = r.x; xw[1] = r.y; xw[2] = r.z; xw[3] = r.w;
    __syncthreads();
    float wv[9];
    #pragma unroll
    for (int k = 0; k < 9; ++k) wv[k] = ldq(wt, (long)c * 9 + k, isf32);
    float acc[4] = {0.f, 0.f, 0.f, 0.f};
    #pragma unroll
    for (int ky = 0; ky < 3; ++ky) {
        int iy = y + ky - 1;
        if (iy < 0 || iy >= 32) continue;
        float row[6];
        #pragma unroll
        for (int i = 0; i < 6; ++i) {
            int ix = x0 + i - 1;
            row[i] = (ix >= 0 && ix < 32) ? xs[iy * 33 + ix] : 0.0f;
        }
        #pragma unroll
        for (int kx = 0; kx < 3; ++kx)
            #pragma unroll
            for (int j = 0; j < 4; ++j)
                acc[j] += row[j + kx] * wv[ky * 3 + kx];
    }
    float* o = g_dw + (size_t)blockIdx.x * HW_ + y * 32 + x0;
    o[0] = acc[0]; o[1] = acc[1]; o[2] = acc[2]; o[3] = acc[3];
}

// ---------------------------------------------------------------------------
// pointwise 1x1 conv on g_dw, COUT=8 -> g_pw + fused stats slot 6
// ---------------------------------------------------------------------------
__global__ __launch_bounds__(256)
void k_pw(const void* __restrict__ wt) {
    if (g_sel[6] == 0.0f) return;
    __shared__ float xs[HW_];
    __shared__ float red[1024];
    const int t = threadIdx.x;
    const int c0 = (blockIdx.x & 31) * 8;
    const int b  = blockIdx.x >> 5;
    const int isf32 = g_isf32;
    const float* hb = g_dw + (size_t)b * C_ * HW_;
    float acc[8][4];
    #pragma unroll
    for (int k = 0; k < 8; ++k)
        #pragma unroll
        for (int j = 0; j < 4; ++j) acc[k][j] = 0.f;
    for (int ci = 0; ci < C_; ++ci) {
        __syncthreads();
        float4 r = *(const float4*)(hb + (size_t)ci * HW_ + t * 4);
        xs[t*4+0] = r.x; xs[t*4+1] = r.y; xs[t*4+2] = r.z; xs[t*4+3] = r.w;
        __syncthreads();
        const float x0v = xs[t], x1v = xs[t + 256], x2v = xs[t + 512], x3v = xs[t + 768];
        #pragma unroll
        for (int k = 0; k < 8; ++k) {
            float wv = ldq(wt, (long)(c0 + k) * C_ + ci, isf32);
            acc[k][0] += x0v * wv; acc[k][1] += x1v * wv;
            acc[k][2] += x2v * wv; acc[k][3] += x3v * wv;
        }
    }
    #pragma unroll
    for (int k = 0; k < 8; ++k) {
        float* o = g_pw + (size_t)(b * C_ + c0 + k) * HW_;
        o[t] = acc[k][0]; o[t + 256] = acc[k][1];
        o[t + 512] = acc[k][2]; o[t + 768] = acc[k][3];
    }
    #pragma unroll
    for (int k = 0; k < 8; k += 2) {
        float sA  = acc[k][0] + acc[k][1] + acc[k][2] + acc[k][3];
        float s2A = acc[k][0]*acc[k][0] + acc[k][1]*acc[k][1]
                  + acc[k][2]*acc[k][2] + acc[k][3]*acc[k][3];
        float sB  = acc[k+1][0] + acc[k+1][1] + acc[k+1][2] + acc[k+1][3];
        float s2B = acc[k+1][0]*acc[k+1][0] + acc[k+1][1]*acc[k+1][1]
                  + acc[k+1][2]*acc[k+1][2] + acc[k+1][3]*acc[k+1][3];
        stats_ep2(red, t, sA, s2A, sB, s2B, c0 + k, c0 + k + 1, 6);
    }
}

// ---------------------------------------------------------------------------
// single fused epilogue: out = sel3*h + Σ sel_k * BN_k(buf_k), dtype-dual
// ---------------------------------------------------------------------------
__device__ __forceinline__ void bn_term(float4& o, const float* buf, size_t idx,
                                        int c, int slot, float sv,
                                        const void* g, const void* bb, int isf32) {
    float mean = g_stats[slot * 512 + c] * (1.0f / NPC_);
    float var  = g_stats[slot * 512 + 256 + c] * (1.0f / NPC_) - mean * mean;
    float rstd = rsqrtf(fmaxf(var, 0.f) + 1e-5f);
    float gv = ldq(g, c, isf32), bv = ldq(bb, c, isf32);
    float4 r = *(const float4*)(buf + idx);
    o.x += sv * ((r.x - mean) * rstd * gv + bv);
    o.y += sv * ((r.y - mean) * rstd * gv + bv);
    o.z += sv * ((r.z - mean) * rstd * gv + bv);
    o.w += sv * ((r.w - mean) * rstd * gv + bv);
}

__global__ __launch_bounds__(256)
void k_final_all(void* __restrict__ out,
                 const void* __restrict__ gmp, const void* __restrict__ bmp,
                 const void* __restrict__ gap, const void* __restrict__ bap,
                 const void* __restrict__ g3,  const void* __restrict__ b3,
                 const void* __restrict__ g5,  const void* __restrict__ b5,
                 const void* __restrict__ gs,  const void* __restrict__ bs,
                 const void* __restrict__ gd,  const void* __restrict__ bd) {
    size_t idx = ((size_t)blockIdx.x * 256 + threadIdx.x) * 4;
    int c = (int)((idx >> 10) & (C_ - 1));
    int isf32 = g_isf32;
    float4 o = {0.f, 0.f, 0.f, 0.f};
    float s3 = g_sel[3];
    if (s3 != 0.f) {
        float4 h = *(const float4*)(g_h + idx);
        o.x = s3 * h.x; o.y = s3 * h.y; o.z = s3 * h.z; o.w = s3 * h.w;
    }
    float sv;
    if ((sv = g_sel[1]) != 0.f) bn_term(o, g_pm, idx, c, 1, sv, gmp, bmp, isf32);
    if ((sv = g_sel[2]) != 0.f) bn_term(o, g_pa, idx, c, 2, sv, gap, bap, isf32);
    if ((sv = g_sel[4]) != 0.f) bn_term(o, g_c3, idx, c, 4, sv, g3,  b3,  isf32);
    if ((sv = g_sel[5]) != 0.f) bn_term(o, g_c5, idx, c, 5, sv, g5,  b5,  isf32);
    if ((sv = g_sel[6]) != 0.f) bn_term(o, g_pw, idx, c, 6, sv, gs,  bs,  isf32);
    if ((sv = g_sel[7]) != 0.f) bn_term(o, g_cd, idx, c, 7, sv, gd,  bd,  isf32);
    if (isf32) {
        *(float4*)((float*)out + idx) = o;
    } else {
        ushort4 u; u.x = f2u(o.x); u.y = f2u(o.y); u.z = f2u(o.z); u.w = f2u(o.w);
        *(ushort4*)((unsigned short*)out + idx) = u;
    }
}

// ---------------------------------------------------------------------------
extern "C" void kernel_launch(void* const* d_in, const int* in_sizes, int n_in,
                              void* d_out, int out_size, void* d_ws, size_t ws_size,
                              hipStream_t stream) {
    const void* x    = d_in[0];
    const void* aw   = d_in[1];
    const void* w_in = d_in[2];
    const void* g_in = d_in[3];
    const void* b_in = d_in[4];
    const void* w3   = d_in[5];
    const void* g3   = d_in[6];
    const void* b3   = d_in[7];
    const void* w5   = d_in[8];
    const void* g5   = d_in[9];
    const void* b5   = d_in[10];
    const void* wdw  = d_in[11];
    const void* wpw  = d_in[12];
    const void* gs   = d_in[13];
    const void* bs   = d_in[14];
    const void* wd   = d_in[15];
    const void* gd   = d_in[16];
    const void* bd   = d_in[17];
    const void* gmp  = d_in[18];
    const void* bmp  = d_in[19];
    const void* gap  = d_in[20];
    const void* bap  = d_in[21];

    dim3 Bk(256);
    dim3 Gfull(NB_);    // 16384 elementwise / per-(b,c) blocks
    dim3 Gc8(2048);     // COUT=8 conv blocks (64 b * 32 cg)

    k_prep<<<dim3(1), Bk, 0, stream>>>(x, aw);
    k_wconv<<<dim3(32), Bk, 0, stream>>>(w3, w5, wd, w_in);

    // transition: 1x1 conv (COUT=8, f32 packed weights, dbuf) -> g_dw; BN+ReLU
    k_trans<<<Gc8, Bk, 0, stream>>>(x);
    k_bnrelu<<<Gfull, Bk, 0, stream>>>(g_in, b_in);

    // ops 1+2: fused max/avg pool -> g_pm/g_pa
    k_pool_fused<<<Gfull, Bk, 0, stream>>>();

    // ops 4/5/7: specialized dense convs (each early-exits if not selected)
    k_conv1<3, 1, 1, 4><<<Gc8, Bk, 0, stream>>>();   // conv3x3   -> g_c3
    k_conv1<5, 1, 2, 5><<<Gc8, Bk, 0, stream>>>();   // conv5x5   -> g_c5
    k_conv1<3, 2, 2, 7><<<Gc8, Bk, 0, stream>>>();   // dil conv  -> g_cd

    // op 6: sep_conv_3x3: dw (g_h -> g_dw), pw (g_dw -> g_pw)
    k_dw<<<Gfull, Bk, 0, stream>>>(wdw);
    k_pw<<<Gc8, Bk, 0, stream>>>(wpw);

    // single fused epilogue: out = sel3*h + sum sel_k*BN_k(buf_k)
    k_final_all<<<Gfull, Bk, 0, stream>>>(d_out,
        gmp, bmp, gap, bap, g3, b3, g5, b5, gs, bs, gd, bd);
}

// Round 6
// 1216.489 us; speedup vs baseline: 3.0770x; 1.0024x over previous
//
#include <hip/hip_runtime.h>

#define CIN_  128
#define C_    256
#define HW_   1024      /* 32*32 */
#define NPC_  65536.0f  /* 64*1024 elements per channel for BN stats */
#define NB_   16384     /* 64 batches * 256 channels */

constexpr size_t NELEM = 16777216ull;   // 64*256*32*32

// ---- module-scope device scratch: one buffer per producer (no reuse hazards)
__device__ float g_sel[8];
__device__ float g_stats[8 * 512];      // per-slot: [0..255]=sum, [256..511]=sumsq
__device__ int   g_isf32;
__device__ float g_h[NELEM];            // relu(BN0(trans))
__device__ float g_c3[NELEM];           // conv3x3 out      (slot 4)
__device__ float g_c5[NELEM];           // conv5x5 out      (slot 5)
__device__ float g_cd[NELEM];           // dil conv out     (slot 7)
__device__ float g_pm[NELEM];           // maxpool out      (slot 1)
__device__ float g_pa[NELEM];           // avgpool out      (slot 2)
__device__ float g_pw[NELEM];           // pointwise out    (slot 6)
__device__ float g_dw[NELEM];           // trans tmp, then depthwise out

// ---- prepass-converted f32 weights, packed co-fastest (8 per tap) ----------
// g_w5f: [cg=32][ci=256][tap=25][u=8]  (co = cg*8+u)
// g_w3f/g_wdf: [cg=32][ci=256][tap=9][u=8]
// g_wtf: [cg=32][ci=128][u=8]  g_wpf: [cg=32][ci=256][u=8]
__device__ float g_w5f[32 * 256 * 25 * 8];
__device__ float g_w3f[32 * 256 * 9 * 8];
__device__ float g_wdf[32 * 256 * 9 * 8];
__device__ float g_wtf[32 * 128 * 8];
__device__ float g_wpf[32 * 256 * 8];

__device__ __forceinline__ float u2f(unsigned short u) {
    union { unsigned int i; float f; } x; x.i = ((unsigned int)u) << 16; return x.f;
}
__device__ __forceinline__ unsigned short f2u(float f) {
    union { float f; unsigned int i; } x; x.f = f;
    unsigned int r = x.i + 0x7fffu + ((x.i >> 16) & 1u);  // RNE
    return (unsigned short)(r >> 16);
}
__device__ __forceinline__ float ldq(const void* p, long i, int isf32) {
    return isf32 ? ((const float*)p)[i] : u2f(((const unsigned short*)p)[i]);
}

// 32-FMA block shared by k_trans / k_pw
#define FMA8X4(acc, wq0, wq1, x0v, x1v, x2v, x3v)                                     \
    acc[0][0] += x0v*wq0.x; acc[0][1] += x1v*wq0.x; acc[0][2] += x2v*wq0.x; acc[0][3] += x3v*wq0.x; \
    acc[1][0] += x0v*wq0.y; acc[1][1] += x1v*wq0.y; acc[1][2] += x2v*wq0.y; acc[1][3] += x3v*wq0.y; \
    acc[2][0] += x0v*wq0.z; acc[2][1] += x1v*wq0.z; acc[2][2] += x2v*wq0.z; acc[2][3] += x3v*wq0.z; \
    acc[3][0] += x0v*wq0.w; acc[3][1] += x1v*wq0.w; acc[3][2] += x2v*wq0.w; acc[3][3] += x3v*wq0.w; \
    acc[4][0] += x0v*wq1.x; acc[4][1] += x1v*wq1.x; acc[4][2] += x2v*wq1.x; acc[4][3] += x3v*wq1.x; \
    acc[5][0] += x0v*wq1.y; acc[5][1] += x1v*wq1.y; acc[5][2] += x2v*wq1.y; acc[5][3] += x3v*wq1.y; \
    acc[6][0] += x0v*wq1.z; acc[6][1] += x1v*wq1.z; acc[6][2] += x2v*wq1.z; acc[6][3] += x3v*wq1.z; \
    acc[7][0] += x0v*wq1.w; acc[7][1] += x1v*wq1.w; acc[7][2] += x2v*wq1.w; acc[7][3] += x3v*wq1.w;

// ---------------------------------------------------------------------------
// prep: zero stats, detect input dtype, compute sel
// ---------------------------------------------------------------------------
__global__ void k_prep(const void* __restrict__ x, const void* __restrict__ aw) {
    __shared__ int flag_s;
    __shared__ float red[256];
    const int t = threadIdx.x;
    for (int i = t; i < 8 * 512; i += 256) g_stats[i] = 0.f;
    const unsigned short* xu = (const unsigned short*)x;
    int bad = 0;
    for (int i = t; i < 8192; i += 256) {
        unsigned int e = (xu[i] >> 7) & 0xFFu;
        if (e >= 0xC6u) ++bad;
    }
    red[t] = (float)bad;
    __syncthreads();
    for (int off = 128; off > 0; off >>= 1) {
        if (t < off) red[t] += red[t + off];
        __syncthreads();
    }
    if (t == 0) { flag_s = (red[0] > 4.0f) ? 1 : 0; g_isf32 = flag_s; }
    __syncthreads();
    const int isf32 = flag_s;
    if (t == 0) {
        float w[8];
        float mx = -1e30f;
        for (int i = 0; i < 8; ++i) { w[i] = ldq(aw, i, isf32); mx = fmaxf(mx, w[i]); }
        float s = 0.f;
        for (int i = 0; i < 8; ++i) { w[i] = expf(w[i] - mx); s += w[i]; }
        for (int i = 0; i < 8; ++i) w[i] /= s;
        float sv[8] = {0,0,0,0,0,0,0,0};
        bool used[8] = {false,false,false,false,false,false,false,false};
        for (int k = 0; k < 3; ++k) {          // top-3, first-index tie-break
            int bi = -1; float bv = -1.f;
            for (int i = 0; i < 8; ++i) if (!used[i] && w[i] > bv) { bv = w[i]; bi = i; }
            used[bi] = true; sv[bi] = bv;
        }
        float tot = 0.f;
        for (int i = 0; i < 8; ++i) { if (sv[i] < 0.01f) sv[i] = 0.f; tot += sv[i]; }
        tot = fmaxf(tot, 1e-12f);
        for (int i = 0; i < 8; ++i) g_sel[i] = sv[i] / tot;
    }
}

// ---------------------------------------------------------------------------
// weight prepass: convert to f32, repack co-fastest (2x float4 per (ci,tap)).
// grid = 32 blocks (cg). Runs after k_prep (needs g_isf32).
// ---------------------------------------------------------------------------
__global__ __launch_bounds__(256)
void k_wconv(const void* __restrict__ w3, const void* __restrict__ w5,
             const void* __restrict__ wd, const void* __restrict__ wi,
             const void* __restrict__ wp) {
    const int cg = blockIdx.x;          // 0..31
    const int t  = threadIdx.x;
    const int isf32 = g_isf32;
    // w5: out o = ((ci*25+tap)*8+u)
    for (int o = t; o < 51200; o += 256) {
        int u = o & 7, r = o >> 3, tap = r % 25, ci = r / 25;
        g_w5f[(size_t)cg * 51200 + o] =
            ldq(w5, ((long)(cg * 8 + u) * C_ + ci) * 25 + tap, isf32);
    }
    // w3 / wd: out o = ((ci*9+tap)*8+u)
    for (int o = t; o < 18432; o += 256) {
        int u = o & 7, r = o >> 3, tap = r % 9, ci = r / 9;
        long ii = ((long)(cg * 8 + u) * C_ + ci) * 9 + tap;
        g_w3f[(size_t)cg * 18432 + o] = ldq(w3, ii, isf32);
        g_wdf[(size_t)cg * 18432 + o] = ldq(wd, ii, isf32);
    }
    // transition weights: [cg][ci=128][u=8]
    for (int o = t; o < 1024; o += 256) {
        int u = o & 7, ci = o >> 3;
        g_wtf[cg * 1024 + o] = ldq(wi, (long)(cg * 8 + u) * CIN_ + ci, isf32);
    }
    // pointwise weights: [cg][ci=256][u=8]
    for (int o = t; o < 2048; o += 256) {
        int u = o & 7, ci = o >> 3;
        g_wpf[cg * 2048 + o] = ldq(wp, (long)(cg * 8 + u) * C_ + ci, isf32);
    }
}

// ---------------------------------------------------------------------------
// stats epilogues
// ---------------------------------------------------------------------------
__device__ __forceinline__ void stats_epilogue(float* red, float s, float s2,
                                               int t, int c, int slot) {
    __syncthreads();
    red[t] = s; red[t + 256] = s2;
    __syncthreads();
    for (int off = 128; off > 0; off >>= 1) {
        if (t < off) { red[t] += red[t + off]; red[t + 256] += red[t + 256 + off]; }
        __syncthreads();
    }
    if (t == 0) {
        atomicAdd(&g_stats[slot * 512 + c], red[0]);
        atomicAdd(&g_stats[slot * 512 + 256 + c], red[256]);
    }
}

__device__ __forceinline__ void stats_ep2(float* red, int t,
                                          float sA, float s2A, float sB, float s2B,
                                          int cA, int cB, int slot) {
    __syncthreads();
    red[t] = sA; red[t + 256] = s2A; red[t + 512] = sB; red[t + 768] = s2B;
    __syncthreads();
    for (int off = 128; off > 0; off >>= 1) {
        if (t < off) {
            red[t]       += red[t + off];
            red[t + 256] += red[t + 256 + off];
            red[t + 512] += red[t + 512 + off];
            red[t + 768] += red[t + 768 + off];
        }
        __syncthreads();
    }
    if (t == 0) {
        atomicAdd(&g_stats[slot * 512 + cA],       red[0]);
        atomicAdd(&g_stats[slot * 512 + 256 + cA], red[256]);
        atomicAdd(&g_stats[slot * 512 + cB],       red[512]);
        atomicAdd(&g_stats[slot * 512 + 256 + cB], red[768]);
    }
}

__device__ __forceinline__ void stats_all8(float* red, int t, float acc[8][4],
                                           int c0, int slot) {
    #pragma unroll
    for (int u = 0; u < 8; u += 2)
        stats_ep2(red, t,
            acc[u][0]+acc[u][1]+acc[u][2]+acc[u][3],
            acc[u][0]*acc[u][0]+acc[u][1]*acc[u][1]+acc[u][2]*acc[u][2]+acc[u][3]*acc[u][3],
            acc[u+1][0]+acc[u+1][1]+acc[u+1][2]+acc[u+1][3],
            acc[u+1][0]*acc[u+1][0]+acc[u+1][1]*acc[u+1][1]+acc[u+1][2]*acc[u+1][2]+acc[u+1][3]*acc[u+1][3],
            c0 + u, c0 + u + 1, slot);
}

// ---------------------------------------------------------------------------
// transition 1x1 conv, COUT=8, NO LDS (direct strided global loads — the
// elements each thread needs are thread-private; LDS round-trip was pure cost)
// -> g_dw, stats slot 0. grid = 64 b * 32 cgroups = 2048
// ---------------------------------------------------------------------------
__global__ __launch_bounds__(256)
void k_trans(const void* __restrict__ xin) {
    __shared__ float red[1024];
    const int t  = threadIdx.x;
    const int cg = blockIdx.x & 31;
    const int c0 = cg * 8;
    const int b  = blockIdx.x >> 5;
    const float* wb = g_wtf + cg * 1024;
    float acc[8][4];
    #pragma unroll
    for (int k = 0; k < 8; ++k)
        #pragma unroll
        for (int j = 0; j < 4; ++j) acc[k][j] = 0.f;

    const size_t base0 = (size_t)b * CIN_ * 1024 + t;
    if (g_isf32) {
        const float* xf = (const float*)xin;
        for (int ci = 0; ci < CIN_; ++ci) {
            const float* xp = xf + base0 + (size_t)ci * 1024;
            float x0v = xp[0], x1v = xp[256], x2v = xp[512], x3v = xp[768];
            float4 wq0 = *(const float4*)(wb + ci * 8);
            float4 wq1 = *(const float4*)(wb + ci * 8 + 4);
            FMA8X4(acc, wq0, wq1, x0v, x1v, x2v, x3v)
        }
    } else {
        const unsigned short* xu = (const unsigned short*)xin;
        for (int ci = 0; ci < CIN_; ++ci) {
            const unsigned short* xp = xu + base0 + (size_t)ci * 1024;
            float x0v = u2f(xp[0]),   x1v = u2f(xp[256]);
            float x2v = u2f(xp[512]), x3v = u2f(xp[768]);
            float4 wq0 = *(const float4*)(wb + ci * 8);
            float4 wq1 = *(const float4*)(wb + ci * 8 + 4);
            FMA8X4(acc, wq0, wq1, x0v, x1v, x2v, x3v)
        }
    }
    #pragma unroll
    for (int k = 0; k < 8; ++k) {
        float* o = g_dw + (size_t)(b * C_ + c0 + k) * HW_;
        o[t] = acc[k][0]; o[t + 256] = acc[k][1];
        o[t + 512] = acc[k][2]; o[t + 768] = acc[k][3];
    }
    stats_all8(red, t, acc, c0, 0);
}

// ---------------------------------------------------------------------------
// g_h = relu(BN0(g_dw))
// ---------------------------------------------------------------------------
__global__ __launch_bounds__(256)
void k_bnrelu(const void* __restrict__ g, const void* __restrict__ bb) {
    size_t idx = ((size_t)blockIdx.x * 256 + threadIdx.x) * 4;
    int c = (int)((idx >> 10) & (C_ - 1));
    int isf32 = g_isf32;
    float mean = g_stats[c] * (1.0f / NPC_);
    float var  = g_stats[256 + c] * (1.0f / NPC_) - mean * mean;
    float rstd = rsqrtf(fmaxf(var, 0.f) + 1e-5f);
    float gv = ldq(g, c, isf32), bv = ldq(bb, c, isf32);
    float4 r = *(const float4*)(g_dw + idx);
    float4 h;
    h.x = fmaxf(0.f, (r.x - mean) * rstd * gv + bv);
    h.y = fmaxf(0.f, (r.y - mean) * rstd * gv + bv);
    h.z = fmaxf(0.f, (r.z - mean) * rstd * gv + bv);
    h.w = fmaxf(0.f, (r.w - mean) * rstd * gv + bv);
    *(float4*)(g_h + idx) = h;
}

// ---------------------------------------------------------------------------
// fused max+avg 3x3 pooling on g_h: max -> g_pm (slot 1), avg -> g_pa (slot 2)
// ---------------------------------------------------------------------------
__global__ __launch_bounds__(256)
void k_pool_fused() {
    const float s1 = g_sel[1], s2 = g_sel[2];
    if (s1 == 0.f && s2 == 0.f) return;
    __shared__ float xs[34 * 33];
    __shared__ float red[512];
    const int t = threadIdx.x;
    const int c = blockIdx.x & (C_ - 1);
    const int y  = t >> 3;
    const int x0 = (t & 7) * 4;
    const float* hp = g_h + (size_t)blockIdx.x * HW_;
    float4 r = *(const float4*)(hp + t * 4);
    float* xw = xs + y * 33 + x0;
    xw[0] = r.x; xw[1] = r.y; xw[2] = r.z; xw[3] = r.w;
    __syncthreads();
    float mx[4] = {0.f, 0.f, 0.f, 0.f};       // h >= 0 post-ReLU; matches padded max
    float sm[4] = {0.f, 0.f, 0.f, 0.f};
    #pragma unroll
    for (int ky = 0; ky < 3; ++ky) {
        int iy = y + ky - 1;
        if (iy < 0 || iy >= 32) continue;
        float row[6];
        #pragma unroll
        for (int i = 0; i < 6; ++i) {
            int ix = x0 + i - 1;
            row[i] = (ix >= 0 && ix < 32) ? xs[iy * 33 + ix] : 0.0f;
        }
        #pragma unroll
        for (int kx = 0; kx < 3; ++kx)
            #pragma unroll
            for (int j = 0; j < 4; ++j) {
                mx[j] = fmaxf(mx[j], row[j + kx]);
                sm[j] += row[j + kx];
            }
    }
    #pragma unroll
    for (int j = 0; j < 4; ++j) sm[j] *= (1.0f / 9.0f);
    const size_t ob = (size_t)blockIdx.x * HW_ + y * 32 + x0;
    if (s1 != 0.f) {
        float* o = g_pm + ob;
        o[0] = mx[0]; o[1] = mx[1]; o[2] = mx[2]; o[3] = mx[3];
        stats_epilogue(red, mx[0]+mx[1]+mx[2]+mx[3],
                       mx[0]*mx[0]+mx[1]*mx[1]+mx[2]*mx[2]+mx[3]*mx[3], t, c, 1);
    }
    if (s2 != 0.f) {
        float* o = g_pa + ob;
        o[0] = sm[0]; o[1] = sm[1]; o[2] = sm[2]; o[3] = sm[3];
        stats_epilogue(red, sm[0]+sm[1]+sm[2]+sm[3],
                       sm[0]*sm[0]+sm[1]*sm[1]+sm[2]*sm[2]+sm[3]*sm[3], t, c, 2);
    }
}

// ---------------------------------------------------------------------------
// SPECIALIZED dense conv, COUT=8, WAVE-PRIVATE zero-padded LDS tiles,
// ZERO barriers in the main loop (waves fully decoupled; per-wave dbuf).
// Each wave stages its 8 output rows + 2*PAD halo rows (TRW x 40 tile,
// interior at col 4). grid = 64 b * 32 cg = 2048.
// ---------------------------------------------------------------------------
template<int KS, int DIL, int PAD, int SLOT>
__global__ __launch_bounds__(256)
void k_conv1() {
    if (g_sel[SLOT] == 0.0f) return;
    constexpr int TRW  = 8 + 2 * PAD;       // wave tile rows (incl. halo)
    constexpr int TAPS = KS * KS;
    __shared__ float xs[4][2][TRW * 40];
    const int t  = threadIdx.x;
    const int w  = t >> 6;                   // wave 0..3
    const int l  = t & 63;
    const int cg = blockIdx.x & 31;
    const int c0 = cg * 8;
    const int b  = blockIdx.x >> 5;
    const int y  = l >> 3;                   // wave-local row 0..7
    const int x0 = (l & 7) * 4;
    const int y0 = w * 8;                    // wave's first output row
    const float* hb = g_h + (size_t)b * C_ * HW_;
    const float* wb = (SLOT == 4 ? g_w3f : SLOT == 5 ? g_w5f : g_wdf)
                      + (size_t)cg * (C_ * TAPS * 8);
    float* obuf = (SLOT == 4) ? g_c3 : (SLOT == 5) ? g_c5 : g_cd;

    // each lane stages tile row y (always) and tile row y+8 (if y < 2*PAD)
    const int grA = y0 - PAD + y;            // global row of tile row y
    const bool okA = (grA >= 0) && (grA < 32);
    const int grB = grA + 8;                 // global row of tile row y+8
    const bool okB = (y < 2 * PAD) && (grB < 32);

    float acc[8][4];
    #pragma unroll
    for (int u = 0; u < 8; ++u)
        #pragma unroll
        for (int j = 0; j < 4; ++j) acc[u][j] = 0.f;

    // zero wave-private double buffer (halo/pad stays zero forever)
    {
        float* xw = &xs[w][0][0];
        for (int i = l; i < 2 * TRW * 40; i += 64) xw[i] = 0.f;
    }
    // prologue: stage ci=0 (same-wave LDS ordering; no barrier needed)
    if (okA) *(float4*)(&xs[w][0][y * 40 + 4 + x0]) =
        *(const float4*)(hb + (size_t)grA * 32 + x0);
    if (okB) *(float4*)(&xs[w][0][(y + 8) * 40 + 4 + x0]) =
        *(const float4*)(hb + (size_t)grB * 32 + x0);
    int cur = 0;

    for (int ci = 0; ci < C_; ++ci) {
        // issue next-channel loads EARLY (hide under FMA body)
        float4 rA = {0.f,0.f,0.f,0.f}, rB = {0.f,0.f,0.f,0.f};
        if (ci + 1 < C_) {
            const float* hn = hb + (size_t)(ci + 1) * HW_;
            if (okA) rA = *(const float4*)(hn + grA * 32 + x0);
            if (okB) rB = *(const float4*)(hn + grB * 32 + x0);
        }
        const float* xsc = xs[w][cur];
        const float* wc  = wb + ci * (TAPS * 8);
        #pragma unroll
        for (int ky = 0; ky < KS; ++ky) {
            const int rr = (y + ky * DIL) * 40 + x0;
            // minimal aligned window reads from the zero-padded tile
            float wnd[12];
            if (PAD == 1) {                 // tile cols x0+3..x0+8
                wnd[3] = xsc[rr + 3];
                float4 qb = *(const float4*)(xsc + rr + 4);
                wnd[4] = qb.x; wnd[5] = qb.y; wnd[6] = qb.z; wnd[7] = qb.w;
                wnd[8] = xsc[rr + 8];
            } else {                        // tile cols x0+2..x0+9
                float2 qa = *(const float2*)(xsc + rr + 2);
                float4 qb = *(const float4*)(xsc + rr + 4);
                float2 qc = *(const float2*)(xsc + rr + 8);
                wnd[2] = qa.x; wnd[3] = qa.y;
                wnd[4] = qb.x; wnd[5] = qb.y; wnd[6] = qb.z; wnd[7] = qb.w;
                wnd[8] = qc.x; wnd[9] = qc.y;
            }
            #pragma unroll
            for (int kx = 0; kx < KS; ++kx) {
                const float4 wA = *(const float4*)(wc + (ky * KS + kx) * 8);
                const float4 wB = *(const float4*)(wc + (ky * KS + kx) * 8 + 4);
                #pragma unroll
                for (int j = 0; j < 4; ++j) {
                    const float v = wnd[(4 - PAD) + j + kx * DIL];
                    acc[0][j] += v * wA.x; acc[1][j] += v * wA.y;
                    acc[2][j] += v * wA.z; acc[3][j] += v * wA.w;
                    acc[4][j] += v * wB.x; acc[5][j] += v * wB.y;
                    acc[6][j] += v * wB.z; acc[7][j] += v * wB.w;
                }
            }
        }
        // write-late into the other wave-private buffer (no barrier)
        if (ci + 1 < C_) {
            float* xn = xs[w][cur ^ 1];
            if (okA) *(float4*)(xn + y * 40 + 4 + x0) = rA;
            if (okB) *(float4*)(xn + (y + 8) * 40 + 4 + x0) = rB;
        }
        cur ^= 1;
    }

    #pragma unroll
    for (int u = 0; u < 8; ++u) {
        float4 o; o.x = acc[u][0]; o.y = acc[u][1]; o.z = acc[u][2]; o.w = acc[u][3];
        *(float4*)(obuf + (size_t)(b * C_ + c0 + u) * HW_ + (y0 + y) * 32 + x0) = o;
    }
    // stats: alias red onto xs (safe: stats_ep2 starts with __syncthreads,
    // so every wave's LDS reads are complete before any red write)
    float* red = &xs[0][0][0];
    stats_all8(red, t, acc, c0, SLOT);
}

// ---------------------------------------------------------------------------
// depthwise 3x3: g_h -> g_dw (g_h preserved for the skip term in k_final_all)
// ---------------------------------------------------------------------------
__global__ __launch_bounds__(256)
void k_dw(const void* __restrict__ wt) {
    if (g_sel[6] == 0.0f) return;
    __shared__ float xs[34 * 33];
    const int t = threadIdx.x;
    const int c = blockIdx.x & (C_ - 1);
    const int y  = t >> 3;
    const int x0 = (t & 7) * 4;
    const int isf32 = g_isf32;
    const float* hp = g_h + (size_t)blockIdx.x * HW_;
    float4 r = *(const float4*)(hp + t * 4);
    float* xw = xs + y * 33 + x0;
    xw[0] = r.x; xw[1] = r.y; xw[2] = r.z; xw[3] = r.w;
    __syncthreads();
    float wv[9];
    #pragma unroll
    for (int k = 0; k < 9; ++k) wv[k] = ldq(wt, (long)c * 9 + k, isf32);
    float acc[4] = {0.f, 0.f, 0.f, 0.f};
    #pragma unroll
    for (int ky = 0; ky < 3; ++ky) {
        int iy = y + ky - 1;
        if (iy < 0 || iy >= 32) continue;
        float row[6];
        #pragma unroll
        for (int i = 0; i < 6; ++i) {
            int ix = x0 + i - 1;
            row[i] = (ix >= 0 && ix < 32) ? xs[iy * 33 + ix] : 0.0f;
        }
        #pragma unroll
        for (int kx = 0; kx < 3; ++kx)
            #pragma unroll
            for (int j = 0; j < 4; ++j)
                acc[j] += row[j + kx] * wv[ky * 3 + kx];
    }
    float* o = g_dw + (size_t)blockIdx.x * HW_ + y * 32 + x0;
    o[0] = acc[0]; o[1] = acc[1]; o[2] = acc[2]; o[3] = acc[3];
}

// ---------------------------------------------------------------------------
// pointwise 1x1 conv on g_dw, COUT=8, NO LDS (direct strided global loads),
// packed f32 weights -> g_pw + fused stats slot 6
// ---------------------------------------------------------------------------
__global__ __launch_bounds__(256)
void k_pw() {
    if (g_sel[6] == 0.0f) return;
    __shared__ float red[1024];
    const int t  = threadIdx.x;
    const int cg = blockIdx.x & 31;
    const int c0 = cg * 8;
    const int b  = blockIdx.x >> 5;
    const float* hb = g_dw + (size_t)b * C_ * HW_ + t;
    const float* wb = g_wpf + cg * 2048;
    float acc[8][4];
    #pragma unroll
    for (int k = 0; k < 8; ++k)
        #pragma unroll
        for (int j = 0; j < 4; ++j) acc[k][j] = 0.f;
    for (int ci = 0; ci < C_; ++ci) {
        const float* hp = hb + (size_t)ci * HW_;
        float x0v = hp[0], x1v = hp[256], x2v = hp[512], x3v = hp[768];
        float4 wq0 = *(const float4*)(wb + ci * 8);
        float4 wq1 = *(const float4*)(wb + ci * 8 + 4);
        FMA8X4(acc, wq0, wq1, x0v, x1v, x2v, x3v)
    }
    #pragma unroll
    for (int k = 0; k < 8; ++k) {
        float* o = g_pw + (size_t)(b * C_ + c0 + k) * HW_;
        o[t] = acc[k][0]; o[t + 256] = acc[k][1];
        o[t + 512] = acc[k][2]; o[t + 768] = acc[k][3];
    }
    stats_all8(red, t, acc, c0, 6);
}

// ---------------------------------------------------------------------------
// single fused epilogue: out = sel3*h + Σ sel_k * BN_k(buf_k), dtype-dual
// ---------------------------------------------------------------------------
__device__ __forceinline__ void bn_term(float4& o, const float* buf, size_t idx,
                                        int c, int slot, float sv,
                                        const void* g, const void* bb, int isf32) {
    float mean = g_stats[slot * 512 + c] * (1.0f / NPC_);
    float var  = g_stats[slot * 512 + 256 + c] * (1.0f / NPC_) - mean * mean;
    float rstd = rsqrtf(fmaxf(var, 0.f) + 1e-5f);
    float gv = ldq(g, c, isf32), bv = ldq(bb, c, isf32);
    float4 r = *(const float4*)(buf + idx);
    o.x += sv * ((r.x - mean) * rstd * gv + bv);
    o.y += sv * ((r.y - mean) * rstd * gv + bv);
    o.z += sv * ((r.z - mean) * rstd * gv + bv);
    o.w += sv * ((r.w - mean) * rstd * gv + bv);
}

__global__ __launch_bounds__(256)
void k_final_all(void* __restrict__ out,
                 const void* __restrict__ gmp, const void* __restrict__ bmp,
                 const void* __restrict__ gap, const void* __restrict__ bap,
                 const void* __restrict__ g3,  const void* __restrict__ b3,
                 const void* __restrict__ g5,  const void* __restrict__ b5,
                 const void* __restrict__ gs,  const void* __restrict__ bs,
                 const void* __restrict__ gd,  const void* __restrict__ bd) {
    size_t idx = ((size_t)blockIdx.x * 256 + threadIdx.x) * 4;
    int c = (int)((idx >> 10) & (C_ - 1));
    int isf32 = g_isf32;
    float4 o = {0.f, 0.f, 0.f, 0.f};
    float s3 = g_sel[3];
    if (s3 != 0.f) {
        float4 h = *(const float4*)(g_h + idx);
        o.x = s3 * h.x; o.y = s3 * h.y; o.z = s3 * h.z; o.w = s3 * h.w;
    }
    float sv;
    if ((sv = g_sel[1]) != 0.f) bn_term(o, g_pm, idx, c, 1, sv, gmp, bmp, isf32);
    if ((sv = g_sel[2]) != 0.f) bn_term(o, g_pa, idx, c, 2, sv, gap, bap, isf32);
    if ((sv = g_sel[4]) != 0.f) bn_term(o, g_c3, idx, c, 4, sv, g3,  b3,  isf32);
    if ((sv = g_sel[5]) != 0.f) bn_term(o, g_c5, idx, c, 5, sv, g5,  b5,  isf32);
    if ((sv = g_sel[6]) != 0.f) bn_term(o, g_pw, idx, c, 6, sv, gs,  bs,  isf32);
    if ((sv = g_sel[7]) != 0.f) bn_term(o, g_cd, idx, c, 7, sv, gd,  bd,  isf32);
    if (isf32) {
        *(float4*)((float*)out + idx) = o;
    } else {
        ushort4 u; u.x = f2u(o.x); u.y = f2u(o.y); u.z = f2u(o.z); u.w = f2u(o.w);
        *(ushort4*)((unsigned short*)out + idx) = u;
    }
}

// ---------------------------------------------------------------------------
extern "C" void kernel_launch(void* const* d_in, const int* in_sizes, int n_in,
                              void* d_out, int out_size, void* d_ws, size_t ws_size,
                              hipStream_t stream) {
    const void* x    = d_in[0];
    const void* aw   = d_in[1];
    const void* w_in = d_in[2];
    const void* g_in = d_in[3];
    const void* b_in = d_in[4];
    const void* w3   = d_in[5];
    const void* g3   = d_in[6];
    const void* b3   = d_in[7];
    const void* w5   = d_in[8];
    const void* g5   = d_in[9];
    const void* b5   = d_in[10];
    const void* wdw  = d_in[11];
    const void* wpw  = d_in[12];
    const void* gs   = d_in[13];
    const void* bs   = d_in[14];
    const void* wd   = d_in[15];
    const void* gd   = d_in[16];
    const void* bd   = d_in[17];
    const void* gmp  = d_in[18];
    const void* bmp  = d_in[19];
    const void* gap  = d_in[20];
    const void* bap  = d_in[21];

    dim3 Bk(256);
    dim3 Gfull(NB_);    // 16384 elementwise / per-(b,c) blocks
    dim3 Gc8(2048);     // COUT=8 conv blocks (64 b * 32 cg)

    k_prep<<<dim3(1), Bk, 0, stream>>>(x, aw);
    k_wconv<<<dim3(32), Bk, 0, stream>>>(w3, w5, wd, w_in, wpw);

    // transition: 1x1 conv (COUT=8, no-LDS direct loads) -> g_dw; BN+ReLU
    k_trans<<<Gc8, Bk, 0, stream>>>(x);
    k_bnrelu<<<Gfull, Bk, 0, stream>>>(g_in, b_in);

    // ops 1+2: fused max/avg pool -> g_pm/g_pa
    k_pool_fused<<<Gfull, Bk, 0, stream>>>();

    // ops 4/5/7: specialized dense convs, wave-private barrier-free pipeline
    k_conv1<3, 1, 1, 4><<<Gc8, Bk, 0, stream>>>();   // conv3x3   -> g_c3
    k_conv1<5, 1, 2, 5><<<Gc8, Bk, 0, stream>>>();   // conv5x5   -> g_c5
    k_conv1<3, 2, 2, 7><<<Gc8, Bk, 0, stream>>>();   // dil conv  -> g_cd

    // op 6: sep_conv_3x3: dw (g_h -> g_dw), pw (g_dw -> g_pw, no-LDS)
    k_dw<<<Gfull, Bk, 0, stream>>>(wdw);
    k_pw<<<Gc8, Bk, 0, stream>>>();

    // single fused epilogue: out = sel3*h + sum sel_k*BN_k(buf_k)
    k_final_all<<<Gfull, Bk, 0, stream>>>(d_out,
        gmp, bmp, gap, bap, g3, b3, g5, b5, gs, bs, gd, bd);
}